// Round 2
// baseline (2517.928 us; speedup 1.0000x reference)
//
#include <hip/hip_runtime.h>
#include <stdint.h>

#define D 128

typedef __attribute__((ext_vector_type(8))) short bf16x8;
typedef __attribute__((ext_vector_type(4))) float f32x4;
typedef unsigned short u16;

static __device__ __forceinline__ float b2f(u16 u) {
  return __uint_as_float(((unsigned)u) << 16);
}
static __device__ __forceinline__ u16 f2b(float f) {
  unsigned u = __float_as_uint(f);
  return (u16)((u + 0x7fffu + ((u >> 16) & 1u)) >> 16);
}

// ---------------------------------------------------------------------------
// Fused q-projection weight (fp32 math, bf16 out):
//   M[d][j] = sum_c qw[c][d] * W[c][j]   so  qW = x @ M
// Stored transposed as Mt[c][j][d] ([out][in], torch-Linear layout).
// Fused bias bq[c][j] = qb @ W (kept fp32).
// combo c = type*2 + l  (type 0 = ui: q from user; type 1 = iu: q from item)
// ---------------------------------------------------------------------------
__global__ void prep_fused(const float* __restrict__ qwu, const float* __restrict__ qbu,
                           const float* __restrict__ qwi, const float* __restrict__ qbi,
                           const float* __restrict__ Wui, const float* __restrict__ Wiu,
                           u16* __restrict__ Mt, float* __restrict__ bq) {
  int c = blockIdx.y;    // 0..3
  int d = blockIdx.x;    // 0..127 (input dim of M)
  int j = threadIdx.x;   // 0..127 (output col)
  int l = c & 1, type = c >> 1;
  const float* qw = (type ? qwi : qwu) + l * D * D;
  const float* qb = (type ? qbi : qbu) + l * D;
  const float* W  = (type ? Wiu : Wui) + l * D * D;
  float acc = 0.f;
  for (int cc = 0; cc < D; ++cc) acc += qw[cc * D + d] * W[cc * D + j];
  Mt[((size_t)c * D + j) * D + d] = f2b(acc);
  if (d == 0) {
    float ba = 0.f;
    for (int cc = 0; cc < D; ++cc) ba += qb[cc] * W[cc * D + j];
    bq[c * D + j] = ba;
  }
}

// Convert the 4 k/v weight tensors ([2,D,D] fp32 each) to bf16.
// y: 0=kwu 1=kwi 2=vwu 3=vwi;  dst offset (y*2 + l)*D*D handled by flat copy.
__global__ void cast_w(const float* __restrict__ kwu, const float* __restrict__ kwi,
                       const float* __restrict__ vwu, const float* __restrict__ vwi,
                       u16* __restrict__ Wb) {
  int y = blockIdx.y;
  const float* s = (y == 0) ? kwu : (y == 1) ? kwi : (y == 2) ? vwu : vwi;
  int i = blockIdx.x * 256 + threadIdx.x;  // 0..32767 (= 2*D*D)
  Wb[(size_t)y * 2 * D * D + i] = f2b(s[i]);
}

// fp32 -> bf16 cast, 2 elems/thread (packed 4B store)
__global__ void cast_x(const float* __restrict__ x, u16* __restrict__ xb, int n2) {
  int i = blockIdx.x * 256 + threadIdx.x;
  if (i < n2) {
    float2 v = ((const float2*)x)[i];
    ((unsigned*)xb)[i] = (unsigned)f2b(v.x) | ((unsigned)f2b(v.y) << 16);
  }
}

__global__ void zero_f(float* __restrict__ p, int n) {
  int i = blockIdx.x * 256 + threadIdx.x;
  if (i < n) p[i] = 0.f;
}

// ---------------------------------------------------------------------------
// out[n][j] = bf16( sum_d x[n][d]*wt[j][d] + bias[j] ), bf16 in, fp32 acc.
// wt is [out][in]. 256 thr = 4 waves; wave computes 16 rows x 128 cols via
// 4x8 mfma_f32_16x16x32_bf16.  A: A[m=lane&15][k=quad*8+j];
// B: B[k=quad*8+j][n=lane&15];  C/D: col=lane&15, row=quad*4+reg.
// ---------------------------------------------------------------------------
__global__ __launch_bounds__(256) void gemm_mfma(
    const u16* __restrict__ x, const u16* __restrict__ wt,
    const float* __restrict__ bias, u16* __restrict__ out, int nrows) {
  __shared__ __align__(16) u16 wlds[128 * 136];  // [128 out][128 in], +8 pad
  int t = threadIdx.x;
#pragma unroll
  for (int i = 0; i < 8; ++i) {
    int idx = t + 256 * i;            // 16B chunk id, 0..2047
    int n = idx >> 4, kc = idx & 15;
    ((bf16x8*)wlds)[n * 17 + kc] = ((const bf16x8*)wt)[idx];
  }
  __syncthreads();
  int wave = t >> 6, lane = t & 63;
  int m = lane & 15, quad = lane >> 4;
  int row0 = blockIdx.x * 64 + wave * 16;
  int arow = row0 + m;
  const bf16x8* xv = (const bf16x8*)(x + (size_t)(arow < nrows ? arow : 0) * D);
  f32x4 acc[8];
#pragma unroll
  for (int n = 0; n < 8; ++n) acc[n] = (f32x4){0.f, 0.f, 0.f, 0.f};
#pragma unroll
  for (int kk = 0; kk < 4; ++kk) {
    bf16x8 a = xv[kk * 4 + quad];
#pragma unroll
    for (int n = 0; n < 8; ++n) {
      bf16x8 b = ((const bf16x8*)wlds)[(n * 16 + m) * 17 + kk * 4 + quad];
      acc[n] = __builtin_amdgcn_mfma_f32_16x16x32_bf16(a, b, acc[n], 0, 0, 0);
    }
  }
#pragma unroll
  for (int n = 0; n < 8; ++n) {
    float bb = bias[n * 16 + m];
#pragma unroll
    for (int r = 0; r < 4; ++r) {
      int orow = row0 + quad * 4 + r;
      if (orow < nrows) out[(size_t)orow * D + n * 16 + m] = f2b(acc[n][r] + bb);
    }
  }
}

// ---------------------------------------------------------------------------
// One pass per edge type: score -> exp -> scatter exp(s)*v[src] into agg[dst]
// (fp32 atomics) + distributed partials of sum(exp) for the global softmax Z.
// One wave per edge, 2 feature dims per lane.
// ---------------------------------------------------------------------------
__global__ __launch_bounds__(256) void edge_pass(
    const u16* __restrict__ Pq, const u16* __restrict__ Pk, const u16* __restrict__ Pv,
    const int* __restrict__ src, const int* __restrict__ dst,
    float* __restrict__ agg, float* __restrict__ zpart, int E) {
  int e = blockIdx.x * 4 + (threadIdx.x >> 6);
  int lane = threadIdx.x & 63;
  float p = 0.f;
  if (e < E) {
    int s = src[e], d2 = dst[e];
    ushort2 qa = ((const ushort2*)(Pq + (size_t)s * D))[lane];
    ushort2 ka = ((const ushort2*)(Pk + (size_t)d2 * D))[lane];
    float dot = b2f(qa.x) * b2f(ka.x) + b2f(qa.y) * b2f(ka.y);
#pragma unroll
    for (int off = 32; off > 0; off >>= 1) dot += __shfl_xor(dot, off, 64);
    float sc = dot * 0.08838834764831845f;  // 1/sqrt(128)
    sc = (sc > 0.f) ? sc : 0.01f * sc;      // leaky_relu
    p = __expf(sc);                         // scores ~N(0,1): no max-sub needed
    ushort2 va = ((const ushort2*)(Pv + (size_t)s * D))[lane];
    float* ap = agg + (size_t)d2 * D + lane * 2;
    unsafeAtomicAdd(ap, p * b2f(va.x));
    unsafeAtomicAdd(ap + 1, p * b2f(va.y));
  }
  __shared__ float ps[4];
  if (lane == 0) ps[threadIdx.x >> 6] = p;
  __syncthreads();
  if (threadIdx.x == 0)
    unsafeAtomicAdd(&zpart[blockIdx.x & 1023], ps[0] + ps[1] + ps[2] + ps[3]);
}

// block 0: zinv[0] = 1/sum(zpart[0:1024]) (ui edges); block 1: iu edges
__global__ void zreduce(const float* __restrict__ zpart, float* __restrict__ zinv) {
  const float* zp = zpart + blockIdx.x * 1024;
  int t = threadIdx.x;
  float s = 0.f;
  for (int i = t; i < 1024; i += 256) s += zp[i];
  __shared__ float red[256];
  red[t] = s;
  __syncthreads();
  for (int k = 128; k > 0; k >>= 1) {
    if (t < k) red[t] += red[t + k];
    __syncthreads();
  }
  if (t == 0) zinv[blockIdx.x] = 1.0f / red[0];
}

// out = x_in + agg * zinv  (fp32); optionally also write bf16 mirror for the
// next layer's GEMM inputs.
__global__ void update_x(const float* __restrict__ xu, const float* __restrict__ xi,
                         const float* __restrict__ aggu, const float* __restrict__ aggi,
                         const float* __restrict__ zinv,
                         float* __restrict__ ou, float* __restrict__ oi,
                         u16* __restrict__ bu, u16* __restrict__ bi,
                         int nu, int ni, int wb) {
  int i = blockIdx.x * 256 + threadIdx.x;
  float zu = zinv[1];  // agg_u accumulated from iu edges
  float zi = zinv[0];  // agg_i accumulated from ui edges
  if (i < nu) {
    float v = xu[i] + aggu[i] * zu;
    ou[i] = v;
    if (wb) bu[i] = f2b(v);
  } else if (i < nu + ni) {
    int j = i - nu;
    float v = xi[j] + aggi[j] * zi;
    oi[j] = v;
    if (wb) bi[j] = f2b(v);
  }
}

extern "C" void kernel_launch(void* const* d_in, const int* in_sizes, int n_in,
                              void* d_out, int out_size, void* d_ws, size_t ws_size,
                              hipStream_t stream) {
  const float* xu_in = (const float*)d_in[0];
  const float* xi_in = (const float*)d_in[1];
  const int* ei_ui = (const int*)d_in[2];
  const int* ei_iu = (const int*)d_in[3];
  const float* qwu = (const float*)d_in[4];
  const float* qbu = (const float*)d_in[5];
  const float* kwu = (const float*)d_in[6];
  const float* kbu = (const float*)d_in[7];
  const float* vwu = (const float*)d_in[8];
  const float* vbu = (const float*)d_in[9];
  const float* qwi = (const float*)d_in[10];
  const float* qbi = (const float*)d_in[11];
  const float* kwi = (const float*)d_in[12];
  const float* kbi = (const float*)d_in[13];
  const float* vwi = (const float*)d_in[14];
  const float* vbi = (const float*)d_in[15];
  const float* Wui = (const float*)d_in[16];
  const float* Wiu = (const float*)d_in[17];

  int NU = in_sizes[0] / D;
  int NI = in_sizes[1] / D;
  int E  = in_sizes[2] / 2;
  int NM = (NU > NI) ? NU : NI;

  // workspace layout (all 16B-aligned)
  char* w = (char*)d_ws;
  float* agg_u = (float*)w;  w += (size_t)NU * D * 4;
  float* agg_i = (float*)w;  w += (size_t)NI * D * 4;
  float* zpart = (float*)w;  w += 2048 * 4;        // contiguous with agg for zeroing
  float* zinv  = (float*)w;  w += 64;
  float* bq    = (float*)w;  w += 4 * D * 4;
  u16* Mt  = (u16*)w;        w += (size_t)4 * D * D * 2;
  u16* Wb  = (u16*)w;        w += (size_t)8 * D * D * 2;  // kwu,kwi,vwu,vwi x 2 layers
  u16* xub = (u16*)w;        w += (size_t)NU * D * 2;
  u16* xib = (u16*)w;        w += (size_t)NI * D * 2;
  u16* Pq  = (u16*)w;        w += (size_t)NM * D * 2;
  u16* Pk  = (u16*)w;        w += (size_t)NM * D * 2;
  u16* Pv  = (u16*)w;

  float* out_u = (float*)d_out;
  float* out_i = out_u + (size_t)NU * D;

  prep_fused<<<dim3(128, 4), 128, 0, stream>>>(qwu, qbu, qwi, qbi, Wui, Wiu, Mt, bq);
  cast_w<<<dim3(128, 4), 256, 0, stream>>>(kwu, kwi, vwu, vwi, Wb);
  cast_x<<<(NU * D / 2 + 255) / 256, 256, 0, stream>>>(xu_in, xub, NU * D / 2);
  cast_x<<<(NI * D / 2 + 255) / 256, 256, 0, stream>>>(xi_in, xib, NI * D / 2);

  int zn = NU * D + NI * D + 2048;
  int gu = (NU + 63) / 64, gi = (NI + 63) / 64;
  int ge = (E + 3) / 4;
  int gup = (NU * D + NI * D + 255) / 256;

  for (int l = 0; l < 2; ++l) {
    zero_f<<<(zn + 255) / 256, 256, 0, stream>>>(agg_u, zn);
    // edge type ui (user -> item): q,v from user, k from item
    gemm_mfma<<<gu, 256, 0, stream>>>(xub, Mt + (size_t)l * D * D,      bq + l * D, Pq, NU);
    gemm_mfma<<<gi, 256, 0, stream>>>(xib, Wb + (size_t)(2 + l) * D * D, kbi + l * D, Pk, NI);
    gemm_mfma<<<gu, 256, 0, stream>>>(xub, Wb + (size_t)(4 + l) * D * D, vbu + l * D, Pv, NU);
    edge_pass<<<ge, 256, 0, stream>>>(Pq, Pk, Pv, ei_ui, ei_ui + E, agg_i, zpart, E);
    // edge type iu (item -> user): q,v from item, k from user
    gemm_mfma<<<gi, 256, 0, stream>>>(xib, Mt + (size_t)(2 + l) * D * D, bq + (2 + l) * D, Pq, NI);
    gemm_mfma<<<gu, 256, 0, stream>>>(xub, Wb + (size_t)(0 + l) * D * D, kbu + l * D, Pk, NU);
    gemm_mfma<<<gi, 256, 0, stream>>>(xib, Wb + (size_t)(6 + l) * D * D, vbi + l * D, Pv, NI);
    edge_pass<<<ge, 256, 0, stream>>>(Pq, Pk, Pv, ei_iu, ei_iu + E, agg_u, zpart + 1024, E);

    zreduce<<<2, 256, 0, stream>>>(zpart, zinv);
    if (l == 0)
      update_x<<<gup, 256, 0, stream>>>(xu_in, xi_in, agg_u, agg_i, zinv,
                                        out_u, out_i, xub, xib, NU * D, NI * D, 1);
    else
      update_x<<<gup, 256, 0, stream>>>(out_u, out_i, agg_u, agg_i, zinv,
                                        out_u, out_i, nullptr, nullptr, NU * D, NI * D, 0);
  }
}

// Round 3
// 931.999 us; speedup vs baseline: 2.7016x; 2.7016x over previous
//
#include <hip/hip_runtime.h>
#include <stdint.h>

#define D 128

typedef __attribute__((ext_vector_type(8))) short bf16x8;
typedef __attribute__((ext_vector_type(4))) float f32x4;
typedef unsigned short u16;

static __device__ __forceinline__ float b2f(u16 u) {
  return __uint_as_float(((unsigned)u) << 16);
}
static __device__ __forceinline__ u16 f2b(float f) {
  unsigned u = __float_as_uint(f);
  return (u16)((u + 0x7fffu + ((u >> 16) & 1u)) >> 16);
}

// ---------------------------------------------------------------------------
// Fused q-projection weight (fp32 math, bf16 out):
//   M[d][j] = sum_c qw[c][d] * W[c][j]   so  qW = x @ M
// Stored transposed as Mt[c][j][d] ([out][in], torch-Linear layout).
// Fused bias bq[c][j] = qb @ W (fp32).
// combo c = type*2 + l  (type 0 = ui: q from user; type 1 = iu: q from item)
// ---------------------------------------------------------------------------
__global__ void prep_fused(const float* __restrict__ qwu, const float* __restrict__ qbu,
                           const float* __restrict__ qwi, const float* __restrict__ qbi,
                           const float* __restrict__ Wui, const float* __restrict__ Wiu,
                           u16* __restrict__ Mt, float* __restrict__ bq) {
  int c = blockIdx.y;    // 0..3
  int d = blockIdx.x;    // 0..127 (input dim of M)
  int j = threadIdx.x;   // 0..127 (output col)
  int l = c & 1, type = c >> 1;
  const float* qw = (type ? qwi : qwu) + l * D * D;
  const float* qb = (type ? qbi : qbu) + l * D;
  const float* W  = (type ? Wiu : Wui) + l * D * D;
  float acc = 0.f;
  for (int cc = 0; cc < D; ++cc) acc += qw[cc * D + d] * W[cc * D + j];
  Mt[((size_t)c * D + j) * D + d] = f2b(acc);
  if (d == 0) {
    float ba = 0.f;
    for (int cc = 0; cc < D; ++cc) ba += qb[cc] * W[cc * D + j];
    bq[c * D + j] = ba;
  }
}

// Convert the 4 k/v weight tensors ([2,D,D] fp32 each) to bf16.
__global__ void cast_w(const float* __restrict__ kwu, const float* __restrict__ kwi,
                       const float* __restrict__ vwu, const float* __restrict__ vwi,
                       u16* __restrict__ Wb) {
  int y = blockIdx.y;
  const float* s = (y == 0) ? kwu : (y == 1) ? kwi : (y == 2) ? vwu : vwi;
  int i = blockIdx.x * 256 + threadIdx.x;  // 0..32767 (= 2*D*D)
  Wb[(size_t)y * 2 * D * D + i] = f2b(s[i]);
}

// fp32 -> bf16 cast, 2 elems/thread (packed 4B store)
__global__ void cast_x(const float* __restrict__ x, u16* __restrict__ xb, int n2) {
  int i = blockIdx.x * 256 + threadIdx.x;
  if (i < n2) {
    float2 v = ((const float2*)x)[i];
    ((unsigned*)xb)[i] = (unsigned)f2b(v.x) | ((unsigned)f2b(v.y) << 16);
  }
}

__global__ void zero_i(int* __restrict__ p, int n) {
  int i = blockIdx.x * 256 + threadIdx.x;
  if (i < n) p[i] = 0;
}

// ----------------------------- CSR build -----------------------------------
__global__ void hist_k(const int* __restrict__ dst, int* __restrict__ counts, int E) {
  int i = blockIdx.x * 256 + threadIdx.x;
  if (i < E) atomicAdd(&counts[dst[i]], 1);
}

// 1 block, 1024 threads: exclusive scan of counts[0..n) -> row_ptr (n+1) and
// woff (scatter cursors; may alias counts — counts read before overwrite).
__global__ __launch_bounds__(1024) void scan_k(const int* __restrict__ counts,
                                               int* __restrict__ row_ptr,
                                               int* __restrict__ woff, int n) {
  __shared__ int sh[1024];
  int t = threadIdx.x;
  int chunk = (n + 1023) >> 10;
  int b = t * chunk;
  int e = b + chunk; if (e > n) e = n;
  int s = 0;
  for (int i = b; i < e; ++i) s += counts[i];
  sh[t] = s;
  __syncthreads();
  for (int off = 1; off < 1024; off <<= 1) {
    int u = (t >= off) ? sh[t - off] : 0;
    __syncthreads();
    sh[t] += u;
    __syncthreads();
  }
  int run = sh[t] - s;  // exclusive prefix at chunk start
  for (int i = b; i < e; ++i) {
    int c = counts[i];        // read BEFORE woff write (woff may alias counts)
    row_ptr[i] = run;
    woff[i] = run;
    run += c;
  }
  if (b < e && e == n) row_ptr[n] = run;
}

__global__ void scatter_k(const int* __restrict__ src, const int* __restrict__ dst,
                          int* __restrict__ woff, int* __restrict__ csr_src, int E) {
  int i = blockIdx.x * 256 + threadIdx.x;
  if (i < E) {
    int p = atomicAdd(&woff[dst[i]], 1);
    csr_src[p] = src[i];
  }
}

// ---------------------------------------------------------------------------
// out[n][j] = bf16( sum_d x[n][d]*wt[j][d] + bias[j] ), bf16 in, fp32 acc.
// wt is [out][in]. 256 thr = 4 waves; wave computes 16 rows x 128 cols via
// 4x8 mfma_f32_16x16x32_bf16.  A: A[m=lane&15][k=quad*8+j];
// B: B[k=quad*8+j][n=lane&15];  C/D: col=lane&15, row=quad*4+reg.
// ---------------------------------------------------------------------------
__global__ __launch_bounds__(256) void gemm_mfma(
    const u16* __restrict__ x, const u16* __restrict__ wt,
    const float* __restrict__ bias, u16* __restrict__ out, int nrows) {
  __shared__ __align__(16) u16 wlds[128 * 136];  // [128 out][128 in], +8 pad
  int t = threadIdx.x;
#pragma unroll
  for (int i = 0; i < 8; ++i) {
    int idx = t + 256 * i;            // 16B chunk id, 0..2047
    int n = idx >> 4, kc = idx & 15;
    ((bf16x8*)wlds)[n * 17 + kc] = ((const bf16x8*)wt)[idx];
  }
  __syncthreads();
  int wave = t >> 6, lane = t & 63;
  int m = lane & 15, quad = lane >> 4;
  int row0 = blockIdx.x * 64 + wave * 16;
  int arow = row0 + m;
  const bf16x8* xv = (const bf16x8*)(x + (size_t)(arow < nrows ? arow : 0) * D);
  f32x4 acc[8];
#pragma unroll
  for (int n = 0; n < 8; ++n) acc[n] = (f32x4){0.f, 0.f, 0.f, 0.f};
#pragma unroll
  for (int kk = 0; kk < 4; ++kk) {
    bf16x8 a = xv[kk * 4 + quad];
#pragma unroll
    for (int n = 0; n < 8; ++n) {
      bf16x8 b = ((const bf16x8*)wlds)[(n * 16 + m) * 17 + kk * 4 + quad];
      acc[n] = __builtin_amdgcn_mfma_f32_16x16x32_bf16(a, b, acc[n], 0, 0, 0);
    }
  }
#pragma unroll
  for (int n = 0; n < 8; ++n) {
    float bb = bias[n * 16 + m];
#pragma unroll
    for (int r = 0; r < 4; ++r) {
      int orow = row0 + quad * 4 + r;
      if (orow < nrows) out[(size_t)orow * D + n * 16 + m] = f2b(acc[n][r] + bb);
    }
  }
}

// ---------------------------------------------------------------------------
// CSR aggregation: one wave per dst node, NO atomics on agg.
// 16 lanes per edge (8 dims each), 4 edges in flight per wave.
// agg[d] = sum_{e in row d} exp(leaky(q[src_e].k[d]/sqrt(D))) * v[src_e]
// z partial (sum of exp) -> per-block atomic into zpart slot.
// ---------------------------------------------------------------------------
__global__ __launch_bounds__(256) void agg_pass(
    const u16* __restrict__ Pq, const u16* __restrict__ Pk, const u16* __restrict__ Pv,
    const int* __restrict__ row_ptr, const int* __restrict__ csr_src,
    float* __restrict__ agg, float* __restrict__ zpart, int ndst) {
  int wave = threadIdx.x >> 6, lane = threadIdx.x & 63;
  int d = blockIdx.x * 4 + wave;
  int sub = lane & 15;   // lane within edge-group (dims sub*8 .. sub*8+7)
  int quad = lane >> 4;  // which of 4 concurrent edges
  float z = 0.f;
  float acc[8] = {0.f, 0.f, 0.f, 0.f, 0.f, 0.f, 0.f, 0.f};
  if (d < ndst) {
    bf16x8 kf = *(const bf16x8*)(Pk + (size_t)d * D + sub * 8);
    float kx[8];
#pragma unroll
    for (int i = 0; i < 8; ++i) kx[i] = b2f((u16)((short*)&kf)[i]);
    int beg = row_ptr[d], end = row_ptr[d + 1];
    int iters = (end - beg + 3) >> 2;
    for (int it = 0; it < iters; ++it) {
      int j = beg + it * 4 + quad;
      bool act = j < end;
      int s = act ? csr_src[j] : 0;
      bf16x8 qf = *(const bf16x8*)(Pq + (size_t)s * D + sub * 8);
      bf16x8 vf = *(const bf16x8*)(Pv + (size_t)s * D + sub * 8);
      float dot = 0.f;
#pragma unroll
      for (int i = 0; i < 8; ++i) dot = fmaf(b2f((u16)((short*)&qf)[i]), kx[i], dot);
#pragma unroll
      for (int off = 1; off <= 8; off <<= 1) dot += __shfl_xor(dot, off, 64);
      float sc = dot * 0.08838834764831845f;  // 1/sqrt(128)
      sc = (sc > 0.f) ? sc : 0.01f * sc;      // leaky_relu
      float p = act ? __expf(sc) : 0.f;       // scores ~N(0,1): no max-sub needed
      if (sub == 0) z += p;
#pragma unroll
      for (int i = 0; i < 8; ++i) acc[i] = fmaf(p, b2f((u16)((short*)&vf)[i]), acc[i]);
    }
    // combine the 4 quads' partial rows
#pragma unroll
    for (int i = 0; i < 8; ++i) {
      acc[i] += __shfl_xor(acc[i], 16, 64);
      acc[i] += __shfl_xor(acc[i], 32, 64);
    }
    if (quad == 0) {
      float* ap = agg + (size_t)d * D + sub * 8;
      ((f32x4*)ap)[0] = (f32x4){acc[0], acc[1], acc[2], acc[3]};
      ((f32x4*)ap)[1] = (f32x4){acc[4], acc[5], acc[6], acc[7]};
    }
    z += __shfl_xor(z, 16, 64);
    z += __shfl_xor(z, 32, 64);
  }
  __shared__ float ps[4];
  if (lane == 0) ps[wave] = z;  // z total lives in lane 0 of each wave
  __syncthreads();
  if (threadIdx.x == 0)
    unsafeAtomicAdd(&zpart[blockIdx.x & 1023], ps[0] + ps[1] + ps[2] + ps[3]);
}

// zinv[b] = 1 / sum(zpart[b*1024 .. b*1024+1024))
__global__ void zreduce(const float* __restrict__ zpart, float* __restrict__ zinv) {
  const float* zp = zpart + blockIdx.x * 1024;
  int t = threadIdx.x;
  float s = 0.f;
  for (int i = t; i < 1024; i += 256) s += zp[i];
  __shared__ float red[256];
  red[t] = s;
  __syncthreads();
  for (int k = 128; k > 0; k >>= 1) {
    if (t < k) red[t] += red[t + k];
    __syncthreads();
  }
  if (t == 0) zinv[blockIdx.x] = 1.0f / red[0];
}

// out = x_in + agg * zinv (fp32); optionally write bf16 mirror for next layer.
__global__ void update_x(const float* __restrict__ xu, const float* __restrict__ xi,
                         const float* __restrict__ aggu, const float* __restrict__ aggi,
                         const float* __restrict__ zinv,
                         float* __restrict__ ou, float* __restrict__ oi,
                         u16* __restrict__ bu, u16* __restrict__ bi,
                         int nu, int ni, int wb) {
  int i = blockIdx.x * 256 + threadIdx.x;
  float zu = zinv[1];  // agg_u accumulated from iu edges
  float zi = zinv[0];  // agg_i accumulated from ui edges
  if (i < nu) {
    float v = xu[i] + aggu[i] * zu;
    ou[i] = v;
    if (wb) bu[i] = f2b(v);
  } else if (i < nu + ni) {
    int j = i - nu;
    float v = xi[j] + aggi[j] * zi;
    oi[j] = v;
    if (wb) bi[j] = f2b(v);
  }
}

extern "C" void kernel_launch(void* const* d_in, const int* in_sizes, int n_in,
                              void* d_out, int out_size, void* d_ws, size_t ws_size,
                              hipStream_t stream) {
  const float* xu_in = (const float*)d_in[0];
  const float* xi_in = (const float*)d_in[1];
  const int* ei_ui = (const int*)d_in[2];
  const int* ei_iu = (const int*)d_in[3];
  const float* qwu = (const float*)d_in[4];
  const float* qbu = (const float*)d_in[5];
  const float* kwu = (const float*)d_in[6];
  const float* kbu = (const float*)d_in[7];
  const float* vwu = (const float*)d_in[8];
  const float* vbu = (const float*)d_in[9];
  const float* qwi = (const float*)d_in[10];
  const float* qbi = (const float*)d_in[11];
  const float* kwi = (const float*)d_in[12];
  const float* kbi = (const float*)d_in[13];
  const float* vwi = (const float*)d_in[14];
  const float* vbi = (const float*)d_in[15];
  const float* Wui = (const float*)d_in[16];
  const float* Wiu = (const float*)d_in[17];

  int NU = in_sizes[0] / D;
  int NI = in_sizes[1] / D;
  int E  = in_sizes[2] / 2;
  int NM = (NU > NI) ? NU : NI;

  // workspace layout (all 16B-aligned)
  char* w = (char*)d_ws;
  float* agg_u = (float*)w;  w += (size_t)NU * D * 4;
  float* agg_i = (float*)w;  w += (size_t)NI * D * 4;
  // zero region: counts_ui, counts_iu, zpart(4 slots x 1024) — contiguous ints
  int* counts_ui = (int*)w;  w += (size_t)NI * 4;
  int* counts_iu = (int*)w;  w += (size_t)NU * 4;
  float* zpart = (float*)w;  w += 4096 * 4;
  float* zinv  = (float*)w;  w += 64;
  float* bq    = (float*)w;  w += 4 * D * 4;
  int* rp_ui = (int*)w;      w += (size_t)(NI + 4) * 4;
  int* rp_iu = (int*)w;      w += (size_t)(NU + 4) * 4;
  int* cs_ui = (int*)w;      w += (size_t)E * 4;
  int* cs_iu = (int*)w;      w += (size_t)E * 4;
  u16* Mt  = (u16*)w;        w += (size_t)4 * D * D * 2;
  u16* Wb  = (u16*)w;        w += (size_t)8 * D * D * 2;  // kwu,kwi,vwu,vwi x 2 layers
  u16* xub = (u16*)w;        w += (size_t)NU * D * 2;
  u16* xib = (u16*)w;        w += (size_t)NI * D * 2;
  u16* Pq  = (u16*)w;        w += (size_t)NM * D * 2;
  u16* Pk  = (u16*)w;        w += (size_t)NM * D * 2;
  u16* Pv  = (u16*)w;

  float* out_u = (float*)d_out;
  float* out_i = out_u + (size_t)NU * D;

  prep_fused<<<dim3(128, 4), 128, 0, stream>>>(qwu, qbu, qwi, qbi, Wui, Wiu, Mt, bq);
  cast_w<<<dim3(128, 4), 256, 0, stream>>>(kwu, kwi, vwu, vwi, Wb);
  cast_x<<<(NU * D / 2 + 255) / 256, 256, 0, stream>>>(xu_in, xub, NU * D / 2);
  cast_x<<<(NI * D / 2 + 255) / 256, 256, 0, stream>>>(xi_in, xib, NI * D / 2);

  // ---- CSR build (edges constant across layers: build once per launch) ----
  int zn = NI + NU + 4096;
  zero_i<<<(zn + 255) / 256, 256, 0, stream>>>(counts_ui, zn);
  int geh = (E + 255) / 256;
  hist_k<<<geh, 256, 0, stream>>>(ei_ui + E, counts_ui, E);
  hist_k<<<geh, 256, 0, stream>>>(ei_iu + E, counts_iu, E);
  scan_k<<<1, 1024, 0, stream>>>(counts_ui, rp_ui, counts_ui, NI);  // woff aliases counts
  scan_k<<<1, 1024, 0, stream>>>(counts_iu, rp_iu, counts_iu, NU);
  scatter_k<<<geh, 256, 0, stream>>>(ei_ui, ei_ui + E, counts_ui, cs_ui, E);
  scatter_k<<<geh, 256, 0, stream>>>(ei_iu, ei_iu + E, counts_iu, cs_iu, E);

  int gu = (NU + 63) / 64, gi = (NI + 63) / 64;
  int gau = (NU + 3) / 4, gai = (NI + 3) / 4;
  int gup = (NU * D + NI * D + 255) / 256;

  for (int l = 0; l < 2; ++l) {
    // edge type ui (user -> item): q,v from user, k from item; dst = item
    gemm_mfma<<<gu, 256, 0, stream>>>(xub, Mt + (size_t)l * D * D,       bq + l * D,  Pq, NU);
    gemm_mfma<<<gi, 256, 0, stream>>>(xib, Wb + (size_t)(2 + l) * D * D, kbi + l * D, Pk, NI);
    gemm_mfma<<<gu, 256, 0, stream>>>(xub, Wb + (size_t)(4 + l) * D * D, vbu + l * D, Pv, NU);
    agg_pass<<<gai, 256, 0, stream>>>(Pq, Pk, Pv, rp_ui, cs_ui, agg_i,
                                      zpart + (size_t)(l * 2 + 0) * 1024, NI);
    // edge type iu (item -> user): q,v from item, k from user; dst = user
    gemm_mfma<<<gi, 256, 0, stream>>>(xib, Mt + (size_t)(2 + l) * D * D, bq + (2 + l) * D, Pq, NI);
    gemm_mfma<<<gu, 256, 0, stream>>>(xub, Wb + (size_t)(0 + l) * D * D, kbu + l * D, Pk, NU);
    gemm_mfma<<<gi, 256, 0, stream>>>(xib, Wb + (size_t)(6 + l) * D * D, vbi + l * D, Pv, NI);
    agg_pass<<<gau, 256, 0, stream>>>(Pq, Pk, Pv, rp_iu, cs_iu, agg_u,
                                      zpart + (size_t)(l * 2 + 1) * 1024, NU);

    zreduce<<<2, 256, 0, stream>>>(zpart + (size_t)l * 2 * 1024, zinv + l * 2);
    if (l == 0)
      update_x<<<gup, 256, 0, stream>>>(xu_in, xi_in, agg_u, agg_i, zinv + l * 2,
                                        out_u, out_i, xub, xib, NU * D, NI * D, 1);
    else
      update_x<<<gup, 256, 0, stream>>>(out_u, out_i, agg_u, agg_i, zinv + l * 2,
                                        out_u, out_i, nullptr, nullptr, NU * D, NI * D, 0);
  }
}

// Round 4
// 738.198 us; speedup vs baseline: 3.4109x; 1.2625x over previous
//
#include <hip/hip_runtime.h>
#include <stdint.h>

#define D 128

typedef __attribute__((ext_vector_type(8))) short bf16x8;
typedef __attribute__((ext_vector_type(4))) float f32x4;
typedef unsigned short u16;

static __device__ __forceinline__ float b2f(u16 u) {
  return __uint_as_float(((unsigned)u) << 16);
}
static __device__ __forceinline__ u16 f2b(float f) {
  unsigned u = __float_as_uint(f);
  return (u16)((u + 0x7fffu + ((u >> 16) & 1u)) >> 16);
}

// ---------------------------------------------------------------------------
// Fused q-projection weight (fp32 math, bf16 out):
//   M[d][j] = sum_c qw[c][d] * W[c][j]   so  qW = x @ M
// Stored transposed as Mt[c][j][d] ([out][in], torch-Linear layout).
// Fused bias bq[c][j] = qb @ W (fp32).
// combo c = type*2 + l  (type 0 = ui: q from user; type 1 = iu: q from item)
// ---------------------------------------------------------------------------
__global__ void prep_fused(const float* __restrict__ qwu, const float* __restrict__ qbu,
                           const float* __restrict__ qwi, const float* __restrict__ qbi,
                           const float* __restrict__ Wui, const float* __restrict__ Wiu,
                           u16* __restrict__ Mt, float* __restrict__ bq) {
  int c = blockIdx.y;    // 0..3
  int d = blockIdx.x;    // 0..127 (input dim of M)
  int j = threadIdx.x;   // 0..127 (output col)
  int l = c & 1, type = c >> 1;
  const float* qw = (type ? qwi : qwu) + l * D * D;
  const float* qb = (type ? qbi : qbu) + l * D;
  const float* W  = (type ? Wiu : Wui) + l * D * D;
  float acc = 0.f;
  for (int cc = 0; cc < D; ++cc) acc += qw[cc * D + d] * W[cc * D + j];
  Mt[((size_t)c * D + j) * D + d] = f2b(acc);
  if (d == 0) {
    float ba = 0.f;
    for (int cc = 0; cc < D; ++cc) ba += qb[cc] * W[cc * D + j];
    bq[c * D + j] = ba;
  }
}

// Convert the 4 k/v weight tensors ([2,D,D] fp32 each) to bf16.
__global__ void cast_w(const float* __restrict__ kwu, const float* __restrict__ kwi,
                       const float* __restrict__ vwu, const float* __restrict__ vwi,
                       u16* __restrict__ Wb) {
  int y = blockIdx.y;
  const float* s = (y == 0) ? kwu : (y == 1) ? kwi : (y == 2) ? vwu : vwi;
  int i = blockIdx.x * 256 + threadIdx.x;  // 0..32767 (= 2*D*D)
  Wb[(size_t)y * 2 * D * D + i] = f2b(s[i]);
}

// fp32 -> bf16 cast, 2 elems/thread (packed 4B store)
__global__ void cast_x(const float* __restrict__ x, u16* __restrict__ xb, int n2) {
  int i = blockIdx.x * 256 + threadIdx.x;
  if (i < n2) {
    float2 v = ((const float2*)x)[i];
    ((unsigned*)xb)[i] = (unsigned)f2b(v.x) | ((unsigned)f2b(v.y) << 16);
  }
}

__global__ void zero_i(int* __restrict__ p, int n) {
  int i = blockIdx.x * 256 + threadIdx.x;
  if (i < n) p[i] = 0;
}

// ----------------------------- CSR build -----------------------------------
__global__ void hist_k(const int* __restrict__ dst, int* __restrict__ counts, int E) {
  int i = blockIdx.x * 256 + threadIdx.x;
  if (i < E) atomicAdd(&counts[dst[i]], 1);
}

// Phase A: per-1024-chunk reduction of counts -> bsum[block]
__global__ __launch_bounds__(256) void scan_phaseA(const int* __restrict__ counts,
                                                   int* __restrict__ bsum, int n) {
  int base = blockIdx.x * 1024;
  int t = threadIdx.x;
  int s = 0;
#pragma unroll
  for (int i = 0; i < 4; ++i) {
    int idx = base + t + i * 256;
    if (idx < n) s += counts[idx];
  }
#pragma unroll
  for (int off = 1; off < 64; off <<= 1) s += __shfl_xor(s, off, 64);
  __shared__ int wsm[4];
  if ((t & 63) == 0) wsm[t >> 6] = s;
  __syncthreads();
  if (t == 0) bsum[blockIdx.x] = wsm[0] + wsm[1] + wsm[2] + wsm[3];
}

// Phase B: one block, exclusive scan of bsum[nb] in place (nb <= 1024)
__global__ __launch_bounds__(1024) void scan_phaseB(int* __restrict__ bsum, int nb) {
  __shared__ int sh[1024];
  int t = threadIdx.x;
  int v = (t < nb) ? bsum[t] : 0;
  sh[t] = v;
  __syncthreads();
  for (int off = 1; off < 1024; off <<= 1) {
    int u = (t >= off) ? sh[t - off] : 0;
    __syncthreads();
    sh[t] += u;
    __syncthreads();
  }
  if (t < nb) bsum[t] = sh[t] - v;  // exclusive
}

// Phase C: local exclusive scan of each 1024-chunk + block offset.
// Writes row_ptr[i] and woff[i] (woff may alias counts: each block reads its
// own chunk fully before writing it; chunks are disjoint across blocks).
__global__ __launch_bounds__(256) void scan_phaseC(const int* __restrict__ counts,
                                                   const int* __restrict__ bsum,
                                                   int* __restrict__ row_ptr,
                                                   int* __restrict__ woff, int n, int total) {
  __shared__ int sh[256];
  int base = blockIdx.x * 1024;
  int t = threadIdx.x;
  int i0 = base + t * 4;
  int4 c = {0, 0, 0, 0};
  if (i0 + 3 < n) c = *(const int4*)(counts + i0);
  else {
    if (i0 < n) c.x = counts[i0];
    if (i0 + 1 < n) c.y = counts[i0 + 1];
    if (i0 + 2 < n) c.z = counts[i0 + 2];
    if (i0 + 3 < n) c.w = counts[i0 + 3];
  }
  int s = c.x + c.y + c.z + c.w;
  sh[t] = s;
  __syncthreads();
  for (int off = 1; off < 256; off <<= 1) {
    int u = (t >= off) ? sh[t - off] : 0;
    __syncthreads();
    sh[t] += u;
    __syncthreads();
  }
  int run = bsum[blockIdx.x] + sh[t] - s;
  int p1 = run + c.x, p2 = p1 + c.y, p3 = p2 + c.z;
  if (i0 < n)     { row_ptr[i0] = run;    woff[i0] = run; }
  if (i0 + 1 < n) { row_ptr[i0 + 1] = p1; woff[i0 + 1] = p1; }
  if (i0 + 2 < n) { row_ptr[i0 + 2] = p2; woff[i0 + 2] = p2; }
  if (i0 + 3 < n) { row_ptr[i0 + 3] = p3; woff[i0 + 3] = p3; }
  if (blockIdx.x == 0 && t == 0) row_ptr[n] = total;  // total edges, known
}

__global__ void scatter_k(const int* __restrict__ src, const int* __restrict__ dst,
                          int* __restrict__ woff, int* __restrict__ csr_src, int E) {
  int i = blockIdx.x * 256 + threadIdx.x;
  if (i < E) {
    int p = atomicAdd(&woff[dst[i]], 1);
    csr_src[p] = src[i];
  }
}

// ---------------------------------------------------------------------------
// out[n][j] = bf16( sum_d x[n][d]*wt[j][d] + bias[j] ), bf16 in, fp32 acc.
// wt is [out][in]. 256 thr = 4 waves; wave computes 16 rows x 128 cols via
// 4x8 mfma_f32_16x16x32_bf16.  A: A[m=lane&15][k=quad*8+j];
// B: B[k=quad*8+j][n=lane&15];  C/D: col=lane&15, row=quad*4+reg.
// ---------------------------------------------------------------------------
__global__ __launch_bounds__(256) void gemm_mfma(
    const u16* __restrict__ x, const u16* __restrict__ wt,
    const float* __restrict__ bias, u16* __restrict__ out, int nrows) {
  __shared__ __align__(16) u16 wlds[128 * 136];  // [128 out][128 in], +8 pad
  int t = threadIdx.x;
#pragma unroll
  for (int i = 0; i < 8; ++i) {
    int idx = t + 256 * i;            // 16B chunk id, 0..2047
    int n = idx >> 4, kc = idx & 15;
    ((bf16x8*)wlds)[n * 17 + kc] = ((const bf16x8*)wt)[idx];
  }
  __syncthreads();
  int wave = t >> 6, lane = t & 63;
  int m = lane & 15, quad = lane >> 4;
  int row0 = blockIdx.x * 64 + wave * 16;
  int arow = row0 + m;
  const bf16x8* xv = (const bf16x8*)(x + (size_t)(arow < nrows ? arow : 0) * D);
  f32x4 acc[8];
#pragma unroll
  for (int n = 0; n < 8; ++n) acc[n] = (f32x4){0.f, 0.f, 0.f, 0.f};
#pragma unroll
  for (int kk = 0; kk < 4; ++kk) {
    bf16x8 a = xv[kk * 4 + quad];
#pragma unroll
    for (int n = 0; n < 8; ++n) {
      bf16x8 b = ((const bf16x8*)wlds)[(n * 16 + m) * 17 + kk * 4 + quad];
      acc[n] = __builtin_amdgcn_mfma_f32_16x16x32_bf16(a, b, acc[n], 0, 0, 0);
    }
  }
#pragma unroll
  for (int n = 0; n < 8; ++n) {
    float bb = bias[n * 16 + m];
#pragma unroll
    for (int r = 0; r < 4; ++r) {
      int orow = row0 + quad * 4 + r;
      if (orow < nrows) out[(size_t)orow * D + n * 16 + m] = f2b(acc[n][r] + bb);
    }
  }
}

// ---------------------------------------------------------------------------
// CSR aggregation: one wave per dst node, NO atomics on agg.
// 16 lanes per edge (8 dims each), 4 edges in flight per wave.
// agg[d] = sum_{e in row d} exp(leaky(q[src_e].k[d]/sqrt(D))) * v[src_e]
// z partial (sum of exp) -> per-block atomic into zpart slot.
// ---------------------------------------------------------------------------
__global__ __launch_bounds__(256) void agg_pass(
    const u16* __restrict__ Pq, const u16* __restrict__ Pk, const u16* __restrict__ Pv,
    const int* __restrict__ row_ptr, const int* __restrict__ csr_src,
    float* __restrict__ agg, float* __restrict__ zpart, int ndst) {
  int wave = threadIdx.x >> 6, lane = threadIdx.x & 63;
  int d = blockIdx.x * 4 + wave;
  int sub = lane & 15;   // lane within edge-group (dims sub*8 .. sub*8+7)
  int quad = lane >> 4;  // which of 4 concurrent edges
  float z = 0.f;
  float acc[8] = {0.f, 0.f, 0.f, 0.f, 0.f, 0.f, 0.f, 0.f};
  if (d < ndst) {
    bf16x8 kf = *(const bf16x8*)(Pk + (size_t)d * D + sub * 8);
    float kx[8];
#pragma unroll
    for (int i = 0; i < 8; ++i) kx[i] = b2f((u16)((short*)&kf)[i]);
    int beg = row_ptr[d], end = row_ptr[d + 1];
    int iters = (end - beg + 3) >> 2;
    for (int it = 0; it < iters; ++it) {
      int j = beg + it * 4 + quad;
      bool act = j < end;
      int s = act ? csr_src[j] : 0;
      bf16x8 qf = *(const bf16x8*)(Pq + (size_t)s * D + sub * 8);
      bf16x8 vf = *(const bf16x8*)(Pv + (size_t)s * D + sub * 8);
      float dot = 0.f;
#pragma unroll
      for (int i = 0; i < 8; ++i) dot = fmaf(b2f((u16)((short*)&qf)[i]), kx[i], dot);
#pragma unroll
      for (int off = 1; off <= 8; off <<= 1) dot += __shfl_xor(dot, off, 64);
      float sc = dot * 0.08838834764831845f;  // 1/sqrt(128)
      sc = (sc > 0.f) ? sc : 0.01f * sc;      // leaky_relu
      float p = act ? __expf(sc) : 0.f;       // scores ~N(0,1): no max-sub needed
      if (sub == 0) z += p;
#pragma unroll
      for (int i = 0; i < 8; ++i) acc[i] = fmaf(p, b2f((u16)((short*)&vf)[i]), acc[i]);
    }
    // combine the 4 quads' partial rows
#pragma unroll
    for (int i = 0; i < 8; ++i) {
      acc[i] += __shfl_xor(acc[i], 16, 64);
      acc[i] += __shfl_xor(acc[i], 32, 64);
    }
    if (quad == 0) {
      float* ap = agg + (size_t)d * D + sub * 8;
      ((f32x4*)ap)[0] = (f32x4){acc[0], acc[1], acc[2], acc[3]};
      ((f32x4*)ap)[1] = (f32x4){acc[4], acc[5], acc[6], acc[7]};
    }
    z += __shfl_xor(z, 16, 64);
    z += __shfl_xor(z, 32, 64);
  }
  __shared__ float ps[4];
  if (lane == 0) ps[wave] = z;  // z total lives in lane 0 of each wave
  __syncthreads();
  if (threadIdx.x == 0)
    unsafeAtomicAdd(&zpart[blockIdx.x & 1023], ps[0] + ps[1] + ps[2] + ps[3]);
}

// zinv[b] = 1 / sum(zpart[b*1024 .. b*1024+1024))
__global__ void zreduce(const float* __restrict__ zpart, float* __restrict__ zinv) {
  const float* zp = zpart + blockIdx.x * 1024;
  int t = threadIdx.x;
  float s = 0.f;
  for (int i = t; i < 1024; i += 256) s += zp[i];
  __shared__ float red[256];
  red[t] = s;
  __syncthreads();
  for (int k = 128; k > 0; k >>= 1) {
    if (t < k) red[t] += red[t + k];
    __syncthreads();
  }
  if (t == 0) zinv[blockIdx.x] = 1.0f / red[0];
}

// out = x_in + agg * zinv (fp32); optionally write bf16 mirror for next layer.
__global__ void update_x(const float* __restrict__ xu, const float* __restrict__ xi,
                         const float* __restrict__ aggu, const float* __restrict__ aggi,
                         const float* __restrict__ zinv,
                         float* __restrict__ ou, float* __restrict__ oi,
                         u16* __restrict__ bu, u16* __restrict__ bi,
                         int nu, int ni, int wb) {
  int i = blockIdx.x * 256 + threadIdx.x;
  float zu = zinv[1];  // agg_u accumulated from iu edges
  float zi = zinv[0];  // agg_i accumulated from ui edges
  if (i < nu) {
    float v = xu[i] + aggu[i] * zu;
    ou[i] = v;
    if (wb) bu[i] = f2b(v);
  } else if (i < nu + ni) {
    int j = i - nu;
    float v = xi[j] + aggi[j] * zi;
    oi[j] = v;
    if (wb) bi[j] = f2b(v);
  }
}

extern "C" void kernel_launch(void* const* d_in, const int* in_sizes, int n_in,
                              void* d_out, int out_size, void* d_ws, size_t ws_size,
                              hipStream_t stream) {
  const float* xu_in = (const float*)d_in[0];
  const float* xi_in = (const float*)d_in[1];
  const int* ei_ui = (const int*)d_in[2];
  const int* ei_iu = (const int*)d_in[3];
  const float* qwu = (const float*)d_in[4];
  const float* qbu = (const float*)d_in[5];
  const float* kwu = (const float*)d_in[6];
  const float* kbu = (const float*)d_in[7];
  const float* vwu = (const float*)d_in[8];
  const float* vbu = (const float*)d_in[9];
  const float* qwi = (const float*)d_in[10];
  const float* qbi = (const float*)d_in[11];
  const float* kwi = (const float*)d_in[12];
  const float* kbi = (const float*)d_in[13];
  const float* vwi = (const float*)d_in[14];
  const float* vbi = (const float*)d_in[15];
  const float* Wui = (const float*)d_in[16];
  const float* Wiu = (const float*)d_in[17];

  int NU = in_sizes[0] / D;
  int NI = in_sizes[1] / D;
  int E  = in_sizes[2] / 2;
  int NM = (NU > NI) ? NU : NI;

  // workspace layout (all 16B-aligned)
  char* w = (char*)d_ws;
  float* agg_u = (float*)w;  w += (size_t)NU * D * 4;
  float* agg_i = (float*)w;  w += (size_t)NI * D * 4;
  // zero region: counts_ui, counts_iu, zpart(4 slots x 1024) — contiguous ints
  int* counts_ui = (int*)w;  w += (size_t)NI * 4;
  int* counts_iu = (int*)w;  w += (size_t)NU * 4;
  float* zpart = (float*)w;  w += 4096 * 4;
  float* zinv  = (float*)w;  w += 64;
  float* bq    = (float*)w;  w += 4 * D * 4;
  int* bsum_ui = (int*)w;    w += 1024 * 4;
  int* bsum_iu = (int*)w;    w += 1024 * 4;
  int* rp_ui = (int*)w;      w += (size_t)(NI + 4) * 4;
  int* rp_iu = (int*)w;      w += (size_t)(NU + 4) * 4;
  int* cs_ui = (int*)w;      w += (size_t)E * 4;
  int* cs_iu = (int*)w;      w += (size_t)E * 4;
  u16* Mt  = (u16*)w;        w += (size_t)4 * D * D * 2;
  u16* Wb  = (u16*)w;        w += (size_t)8 * D * D * 2;  // kwu,kwi,vwu,vwi x 2 layers
  u16* xub = (u16*)w;        w += (size_t)NU * D * 2;
  u16* xib = (u16*)w;        w += (size_t)NI * D * 2;
  u16* Pq  = (u16*)w;        w += (size_t)NM * D * 2;
  u16* Pk  = (u16*)w;        w += (size_t)NM * D * 2;
  u16* Pv  = (u16*)w;

  float* out_u = (float*)d_out;
  float* out_i = out_u + (size_t)NU * D;

  prep_fused<<<dim3(128, 4), 128, 0, stream>>>(qwu, qbu, qwi, qbi, Wui, Wiu, Mt, bq);
  cast_w<<<dim3(128, 4), 256, 0, stream>>>(kwu, kwi, vwu, vwi, Wb);
  cast_x<<<(NU * D / 2 + 255) / 256, 256, 0, stream>>>(xu_in, xub, NU * D / 2);
  cast_x<<<(NI * D / 2 + 255) / 256, 256, 0, stream>>>(xi_in, xib, NI * D / 2);

  // ---- CSR build (edges constant across layers: build once per launch) ----
  int zn = NI + NU + 4096;
  zero_i<<<(zn + 255) / 256, 256, 0, stream>>>(counts_ui, zn);
  int geh = (E + 255) / 256;
  hist_k<<<geh, 256, 0, stream>>>(ei_ui + E, counts_ui, E);
  hist_k<<<geh, 256, 0, stream>>>(ei_iu + E, counts_iu, E);
  int nbi = (NI + 1023) / 1024, nbu = (NU + 1023) / 1024;
  scan_phaseA<<<nbi, 256, 0, stream>>>(counts_ui, bsum_ui, NI);
  scan_phaseA<<<nbu, 256, 0, stream>>>(counts_iu, bsum_iu, NU);
  scan_phaseB<<<1, 1024, 0, stream>>>(bsum_ui, nbi);
  scan_phaseB<<<1, 1024, 0, stream>>>(bsum_iu, nbu);
  scan_phaseC<<<nbi, 256, 0, stream>>>(counts_ui, bsum_ui, rp_ui, counts_ui, NI, E);
  scan_phaseC<<<nbu, 256, 0, stream>>>(counts_iu, bsum_iu, rp_iu, counts_iu, NU, E);
  scatter_k<<<geh, 256, 0, stream>>>(ei_ui, ei_ui + E, counts_ui, cs_ui, E);
  scatter_k<<<geh, 256, 0, stream>>>(ei_iu, ei_iu + E, counts_iu, cs_iu, E);

  int gu = (NU + 63) / 64, gi = (NI + 63) / 64;
  int gau = (NU + 3) / 4, gai = (NI + 3) / 4;
  int gup = (NU * D + NI * D + 255) / 256;

  for (int l = 0; l < 2; ++l) {
    // edge type ui (user -> item): q,v from user, k from item; dst = item
    gemm_mfma<<<gu, 256, 0, stream>>>(xub, Mt + (size_t)l * D * D,       bq + l * D,  Pq, NU);
    gemm_mfma<<<gi, 256, 0, stream>>>(xib, Wb + (size_t)(2 + l) * D * D, kbi + l * D, Pk, NI);
    gemm_mfma<<<gu, 256, 0, stream>>>(xub, Wb + (size_t)(4 + l) * D * D, vbu + l * D, Pv, NU);
    agg_pass<<<gai, 256, 0, stream>>>(Pq, Pk, Pv, rp_ui, cs_ui, agg_i,
                                      zpart + (size_t)(l * 2 + 0) * 1024, NI);
    // edge type iu (item -> user): q,v from item, k from user; dst = user
    gemm_mfma<<<gi, 256, 0, stream>>>(xib, Mt + (size_t)(2 + l) * D * D, bq + (2 + l) * D, Pq, NI);
    gemm_mfma<<<gu, 256, 0, stream>>>(xub, Wb + (size_t)(0 + l) * D * D, kbu + l * D, Pk, NU);
    gemm_mfma<<<gi, 256, 0, stream>>>(xib, Wb + (size_t)(6 + l) * D * D, vbi + l * D, Pv, NI);
    agg_pass<<<gau, 256, 0, stream>>>(Pq, Pk, Pv, rp_iu, cs_iu, agg_u,
                                      zpart + (size_t)(l * 2 + 1) * 1024, NU);

    zreduce<<<2, 256, 0, stream>>>(zpart + (size_t)l * 2 * 1024, zinv + l * 2);
    if (l == 0)
      update_x<<<gup, 256, 0, stream>>>(xu_in, xi_in, agg_u, agg_i, zinv + l * 2,
                                        out_u, out_i, xub, xib, NU * D, NI * D, 1);
    else
      update_x<<<gup, 256, 0, stream>>>(out_u, out_i, agg_u, agg_i, zinv + l * 2,
                                        out_u, out_i, nullptr, nullptr, NU * D, NI * D, 0);
  }
}

// Round 5
// 620.166 us; speedup vs baseline: 4.0601x; 1.1903x over previous
//
#include <hip/hip_runtime.h>
#include <stdint.h>

#define D 128

typedef __attribute__((ext_vector_type(8))) short bf16x8;
typedef __attribute__((ext_vector_type(4))) float f32x4;
typedef __attribute__((ext_vector_type(2))) float f32x2;
typedef unsigned short u16;
typedef unsigned char u8;

static __device__ __forceinline__ float b2f(u16 u) {
  return __uint_as_float(((unsigned)u) << 16);
}
static __device__ __forceinline__ u16 f2b(float f) {
  unsigned u = __float_as_uint(f);
  return (u16)((u + 0x7fffu + ((u >> 16) & 1u)) >> 16);
}

// ------------------------------ fp8 e4m3 -----------------------------------
#if defined(__has_builtin)
#if __has_builtin(__builtin_amdgcn_cvt_pk_f32_fp8) && __has_builtin(__builtin_amdgcn_cvt_pk_fp8_f32)
#define HW_FP8 1
#endif
#endif

static __device__ __forceinline__ u8 enc_fp8(float f) {
#ifdef HW_FP8
  int p = __builtin_amdgcn_cvt_pk_fp8_f32(f, 0.f, 0, false);
  return (u8)(p & 0xff);
#else
  float a = fabsf(f);
  unsigned s = (__float_as_uint(f) >> 31) << 7;
  if (a < 7.8125e-3f) {
    int m = (int)(a * 512.f + 0.5f);
    if (m > 7) m = 7;
    return (u8)(s | m);
  }
  int e; float mant = frexpf(a, &e);      // a = mant*2^e, mant in [0.5,1)
  int E = e + 6;                          // a = (2*mant)*2^(e-1); bias 7
  int m = (int)((2.f * mant - 1.f) * 8.f + 0.5f);
  if (m == 8) { m = 0; E++; }
  if (E > 15 || (E == 15 && m > 6)) { E = 15; m = 6; }  // clamp 448
  if (E < 1) return (u8)s;
  return (u8)(s | (E << 3) | m);
#endif
}

static __device__ __forceinline__ float dec1_fp8(u8 b) {
  int e = (b >> 3) & 15, m = b & 7;
  float mag = e ? ldexpf((float)(8 + m), e - 10) : ldexpf((float)m, -9);
  return (b & 128) ? -mag : mag;
}

// decode 8 fp8 (packed in uint2) -> float[8]
static __device__ __forceinline__ void dec8_fp8(uint2 w, float* o) {
#ifdef HW_FP8
  f32x2 a = __builtin_amdgcn_cvt_pk_f32_fp8((int)w.x, false);
  f32x2 b = __builtin_amdgcn_cvt_pk_f32_fp8((int)w.x, true);
  f32x2 c = __builtin_amdgcn_cvt_pk_f32_fp8((int)w.y, false);
  f32x2 d = __builtin_amdgcn_cvt_pk_f32_fp8((int)w.y, true);
  o[0] = a.x; o[1] = a.y; o[2] = b.x; o[3] = b.y;
  o[4] = c.x; o[5] = c.y; o[6] = d.x; o[7] = d.y;
#else
  u8* p = (u8*)&w;
#pragma unroll
  for (int i = 0; i < 8; ++i) o[i] = dec1_fp8(p[i]);
#endif
}

// ---------------------------------------------------------------------------
// Fused q-projection weight (fp32 math, bf16 out): M[d][j] = sum_c qw[c][d]*W[c][j]
// Stored transposed Mt[c][j][d]; fused bias bq[c][j] = qb @ W.
// c = type*2 + l (type 0 = ui: q from user; 1 = iu: q from item)
// ---------------------------------------------------------------------------
__global__ void prep_fused(const float* __restrict__ qwu, const float* __restrict__ qbu,
                           const float* __restrict__ qwi, const float* __restrict__ qbi,
                           const float* __restrict__ Wui, const float* __restrict__ Wiu,
                           u16* __restrict__ Mt, float* __restrict__ bq) {
  int c = blockIdx.y, d = blockIdx.x, j = threadIdx.x;
  int l = c & 1, type = c >> 1;
  const float* qw = (type ? qwi : qwu) + l * D * D;
  const float* qb = (type ? qbi : qbu) + l * D;
  const float* W  = (type ? Wiu : Wui) + l * D * D;
  float acc = 0.f;
  for (int cc = 0; cc < D; ++cc) acc += qw[cc * D + d] * W[cc * D + j];
  Mt[((size_t)c * D + j) * D + d] = f2b(acc);
  if (d == 0) {
    float ba = 0.f;
    for (int cc = 0; cc < D; ++cc) ba += qb[cc] * W[cc * D + j];
    bq[c * D + j] = ba;
  }
}

// Convert the 4 k/v weight tensors ([2,D,D] fp32 each) to bf16.
__global__ void cast_w(const float* __restrict__ kwu, const float* __restrict__ kwi,
                       const float* __restrict__ vwu, const float* __restrict__ vwi,
                       u16* __restrict__ Wb) {
  int y = blockIdx.y;
  const float* s = (y == 0) ? kwu : (y == 1) ? kwi : (y == 2) ? vwu : vwi;
  int i = blockIdx.x * 256 + threadIdx.x;
  Wb[(size_t)y * 2 * D * D + i] = f2b(s[i]);
}

__global__ void cast_x(const float* __restrict__ x, u16* __restrict__ xb, int n2) {
  int i = blockIdx.x * 256 + threadIdx.x;
  if (i < n2) {
    float2 v = ((const float2*)x)[i];
    ((unsigned*)xb)[i] = (unsigned)f2b(v.x) | ((unsigned)f2b(v.y) << 16);
  }
}

__global__ void zero_i(int* __restrict__ p, int n) {
  int i = blockIdx.x * 256 + threadIdx.x;
  if (i < n) p[i] = 0;
}

// ----------------------------- CSR build -----------------------------------
__global__ void hist2(const int* __restrict__ dui, const int* __restrict__ diu,
                      int* __restrict__ cui, int* __restrict__ ciu, int E) {
  int i = blockIdx.x * 256 + threadIdx.x;
  if (i < E) {
    atomicAdd(&cui[dui[i]], 1);
    atomicAdd(&ciu[diu[i]], 1);
  }
}

__global__ __launch_bounds__(256) void scan_phaseA(const int* __restrict__ counts,
                                                   int* __restrict__ bsum, int n) {
  int base = blockIdx.x * 1024;
  int t = threadIdx.x;
  int s = 0;
#pragma unroll
  for (int i = 0; i < 4; ++i) {
    int idx = base + t + i * 256;
    if (idx < n) s += counts[idx];
  }
#pragma unroll
  for (int off = 1; off < 64; off <<= 1) s += __shfl_xor(s, off, 64);
  __shared__ int wsm[4];
  if ((t & 63) == 0) wsm[t >> 6] = s;
  __syncthreads();
  if (t == 0) bsum[blockIdx.x] = wsm[0] + wsm[1] + wsm[2] + wsm[3];
}

__global__ __launch_bounds__(1024) void scan_phaseB(int* __restrict__ bsum, int nb) {
  __shared__ int sh[1024];
  int t = threadIdx.x;
  int v = (t < nb) ? bsum[t] : 0;
  sh[t] = v;
  __syncthreads();
  for (int off = 1; off < 1024; off <<= 1) {
    int u = (t >= off) ? sh[t - off] : 0;
    __syncthreads();
    sh[t] += u;
    __syncthreads();
  }
  if (t < nb) bsum[t] = sh[t] - v;
}

__global__ __launch_bounds__(256) void scan_phaseC(const int* __restrict__ counts,
                                                   const int* __restrict__ bsum,
                                                   int* __restrict__ row_ptr,
                                                   int* __restrict__ woff, int n, int total) {
  __shared__ int sh[256];
  int base = blockIdx.x * 1024;
  int t = threadIdx.x;
  int i0 = base + t * 4;
  int4 c = {0, 0, 0, 0};
  if (i0 + 3 < n) c = *(const int4*)(counts + i0);
  else {
    if (i0 < n) c.x = counts[i0];
    if (i0 + 1 < n) c.y = counts[i0 + 1];
    if (i0 + 2 < n) c.z = counts[i0 + 2];
    if (i0 + 3 < n) c.w = counts[i0 + 3];
  }
  int s = c.x + c.y + c.z + c.w;
  sh[t] = s;
  __syncthreads();
  for (int off = 1; off < 256; off <<= 1) {
    int u = (t >= off) ? sh[t - off] : 0;
    __syncthreads();
    sh[t] += u;
    __syncthreads();
  }
  int run = bsum[blockIdx.x] + sh[t] - s;
  int p1 = run + c.x, p2 = p1 + c.y, p3 = p2 + c.z;
  if (i0 < n)     { row_ptr[i0] = run;    woff[i0] = run; }
  if (i0 + 1 < n) { row_ptr[i0 + 1] = p1; woff[i0 + 1] = p1; }
  if (i0 + 2 < n) { row_ptr[i0 + 2] = p2; woff[i0 + 2] = p2; }
  if (i0 + 3 < n) { row_ptr[i0 + 3] = p3; woff[i0 + 3] = p3; }
  if (blockIdx.x == 0 && t == 0) row_ptr[n] = total;
}

__global__ void scatter2(const int* __restrict__ sui, const int* __restrict__ dui,
                         const int* __restrict__ siu, const int* __restrict__ diu,
                         int* __restrict__ wui, int* __restrict__ wiu,
                         int* __restrict__ cs_ui, int* __restrict__ cs_iu, int E) {
  int i = blockIdx.x * 256 + threadIdx.x;
  if (i < E) {
    int p = atomicAdd(&wui[dui[i]], 1);
    cs_ui[p] = sui[i];
    int q = atomicAdd(&wiu[diu[i]], 1);
    cs_iu[q] = siu[i];
  }
}

// ---------------------------------------------------------------------------
// Fused 3-way projection over one source-node set. blockIdx.y picks the
// weight/bias/output: y=0 -> q (fp8 out), y=1 -> k (bf16 out), y=2 -> v (fp8).
// MFMA layouts (m89/m91-verified): A[m=lane&15][k=quad*8+j];
// B[k=quad*8+j][n=lane&15]; C/D: col=lane&15, row=quad*4+reg.
// ---------------------------------------------------------------------------
__global__ __launch_bounds__(256) void gemm3(
    const u16* __restrict__ x,
    const u16* __restrict__ wq, const float* __restrict__ bq_,
    const u16* __restrict__ wk, const float* __restrict__ bk_,
    const u16* __restrict__ wv, const float* __restrict__ bv_,
    u8* __restrict__ Tq, u16* __restrict__ Tk, u8* __restrict__ Tv, int nrows) {
  __shared__ __align__(16) u16 wlds[128 * 136];  // [128 out][128 in], +8 pad
  int y = blockIdx.y;
  const u16* wt = (y == 0) ? wq : (y == 1) ? wk : wv;
  const float* bias = (y == 0) ? bq_ : (y == 1) ? bk_ : bv_;
  int t = threadIdx.x;
#pragma unroll
  for (int i = 0; i < 8; ++i) {
    int idx = t + 256 * i;
    int n = idx >> 4, kc = idx & 15;
    ((bf16x8*)wlds)[n * 17 + kc] = ((const bf16x8*)wt)[idx];
  }
  __syncthreads();
  int wave = t >> 6, lane = t & 63;
  int m = lane & 15, quad = lane >> 4;
  int row0 = blockIdx.x * 64 + wave * 16;
  int arow = row0 + m;
  const bf16x8* xv = (const bf16x8*)(x + (size_t)(arow < nrows ? arow : 0) * D);
  f32x4 acc[8];
#pragma unroll
  for (int n = 0; n < 8; ++n) acc[n] = (f32x4){0.f, 0.f, 0.f, 0.f};
#pragma unroll
  for (int kk = 0; kk < 4; ++kk) {
    bf16x8 a = xv[kk * 4 + quad];
#pragma unroll
    for (int n = 0; n < 8; ++n) {
      bf16x8 b = ((const bf16x8*)wlds)[(n * 16 + m) * 17 + kk * 4 + quad];
      acc[n] = __builtin_amdgcn_mfma_f32_16x16x32_bf16(a, b, acc[n], 0, 0, 0);
    }
  }
  if (y == 1) {
#pragma unroll
    for (int n = 0; n < 8; ++n) {
      float bb = bias[n * 16 + m];
#pragma unroll
      for (int r = 0; r < 4; ++r) {
        int orow = row0 + quad * 4 + r;
        if (orow < nrows) Tk[(size_t)orow * D + n * 16 + m] = f2b(acc[n][r] + bb);
      }
    }
  } else {
    u8* T8 = (y == 0) ? Tq : Tv;
#pragma unroll
    for (int n = 0; n < 8; ++n) {
      float bb = bias[n * 16 + m];
#pragma unroll
      for (int r = 0; r < 4; ++r) {
        int orow = row0 + quad * 4 + r;
        if (orow < nrows) T8[(size_t)orow * D + n * 16 + m] = enc_fp8(acc[n][r] + bb);
      }
    }
  }
}

// ---------------------------------------------------------------------------
// CSR aggregation: one wave per dst node, no atomics on agg. q/v tables fp8
// (128 B/row), k bf16. 16 lanes per edge (8 dims each), 4 edges in flight.
// ---------------------------------------------------------------------------
__global__ __launch_bounds__(256) void agg_pass(
    const u8* __restrict__ Pq, const u16* __restrict__ Pk, const u8* __restrict__ Pv,
    const int* __restrict__ row_ptr, const int* __restrict__ csr_src,
    float* __restrict__ agg, float* __restrict__ zpart, int ndst) {
  int wave = threadIdx.x >> 6, lane = threadIdx.x & 63;
  int d = blockIdx.x * 4 + wave;
  int sub = lane & 15;   // dims sub*8 .. sub*8+7
  int quad = lane >> 4;  // which of 4 concurrent edges
  float z = 0.f;
  float acc[8] = {0.f, 0.f, 0.f, 0.f, 0.f, 0.f, 0.f, 0.f};
  if (d < ndst) {
    bf16x8 kf = *(const bf16x8*)(Pk + (size_t)d * D + sub * 8);
    float kx[8];
#pragma unroll
    for (int i = 0; i < 8; ++i) kx[i] = b2f((u16)((short*)&kf)[i]);
    int beg = row_ptr[d], end = row_ptr[d + 1];
    int iters = (end - beg + 3) >> 2;
    for (int it = 0; it < iters; ++it) {
      int j = beg + it * 4 + quad;
      bool act = j < end;
      int s = act ? csr_src[j] : 0;
      uint2 qw = *(const uint2*)(Pq + (size_t)s * D + sub * 8);
      uint2 vw = *(const uint2*)(Pv + (size_t)s * D + sub * 8);
      float qx[8], vx[8];
      dec8_fp8(qw, qx);
      dec8_fp8(vw, vx);
      float dot = 0.f;
#pragma unroll
      for (int i = 0; i < 8; ++i) dot = fmaf(qx[i], kx[i], dot);
#pragma unroll
      for (int off = 1; off <= 8; off <<= 1) dot += __shfl_xor(dot, off, 64);
      float sc = dot * 0.08838834764831845f;  // 1/sqrt(128)
      sc = (sc > 0.f) ? sc : 0.01f * sc;      // leaky_relu
      float p = act ? __expf(sc) : 0.f;       // scores ~N(0,1): no max-sub
      if (sub == 0) z += p;
#pragma unroll
      for (int i = 0; i < 8; ++i) acc[i] = fmaf(p, vx[i], acc[i]);
    }
#pragma unroll
    for (int i = 0; i < 8; ++i) {
      acc[i] += __shfl_xor(acc[i], 16, 64);
      acc[i] += __shfl_xor(acc[i], 32, 64);
    }
    if (quad == 0) {
      float* ap = agg + (size_t)d * D + sub * 8;
      ((f32x4*)ap)[0] = (f32x4){acc[0], acc[1], acc[2], acc[3]};
      ((f32x4*)ap)[1] = (f32x4){acc[4], acc[5], acc[6], acc[7]};
    }
    z += __shfl_xor(z, 16, 64);
    z += __shfl_xor(z, 32, 64);
  }
  __shared__ float ps[4];
  if (lane == 0) ps[wave] = z;
  __syncthreads();
  if (threadIdx.x == 0)
    unsafeAtomicAdd(&zpart[blockIdx.x & 1023], ps[0] + ps[1] + ps[2] + ps[3]);
}

__global__ void zreduce(const float* __restrict__ zpart, float* __restrict__ zinv) {
  const float* zp = zpart + blockIdx.x * 1024;
  int t = threadIdx.x;
  float s = 0.f;
  for (int i = t; i < 1024; i += 256) s += zp[i];
  __shared__ float red[256];
  red[t] = s;
  __syncthreads();
  for (int k = 128; k > 0; k >>= 1) {
    if (t < k) red[t] += red[t + k];
    __syncthreads();
  }
  if (t == 0) zinv[blockIdx.x] = 1.0f / red[0];
}

__global__ void update_x(const float* __restrict__ xu, const float* __restrict__ xi,
                         const float* __restrict__ aggu, const float* __restrict__ aggi,
                         const float* __restrict__ zinv,
                         float* __restrict__ ou, float* __restrict__ oi,
                         u16* __restrict__ bu, u16* __restrict__ bi,
                         int nu, int ni, int wb) {
  int i = blockIdx.x * 256 + threadIdx.x;
  float zu = zinv[1];  // agg_u from iu edges
  float zi = zinv[0];  // agg_i from ui edges
  if (i < nu) {
    float v = xu[i] + aggu[i] * zu;
    ou[i] = v;
    if (wb) bu[i] = f2b(v);
  } else if (i < nu + ni) {
    int j = i - nu;
    float v = xi[j] + aggi[j] * zi;
    oi[j] = v;
    if (wb) bi[j] = f2b(v);
  }
}

extern "C" void kernel_launch(void* const* d_in, const int* in_sizes, int n_in,
                              void* d_out, int out_size, void* d_ws, size_t ws_size,
                              hipStream_t stream) {
  const float* xu_in = (const float*)d_in[0];
  const float* xi_in = (const float*)d_in[1];
  const int* ei_ui = (const int*)d_in[2];
  const int* ei_iu = (const int*)d_in[3];
  const float* qwu = (const float*)d_in[4];
  const float* qbu = (const float*)d_in[5];
  const float* kwu = (const float*)d_in[6];
  const float* kbu = (const float*)d_in[7];
  const float* vwu = (const float*)d_in[8];
  const float* vbu = (const float*)d_in[9];
  const float* qwi = (const float*)d_in[10];
  const float* qbi = (const float*)d_in[11];
  const float* kwi = (const float*)d_in[12];
  const float* kbi = (const float*)d_in[13];
  const float* vwi = (const float*)d_in[14];
  const float* vbi = (const float*)d_in[15];
  const float* Wui = (const float*)d_in[16];
  const float* Wiu = (const float*)d_in[17];

  int NU = in_sizes[0] / D;
  int NI = in_sizes[1] / D;
  int E  = in_sizes[2] / 2;

  // workspace layout (16B-aligned chunks)
  char* w = (char*)d_ws;
  float* agg_u = (float*)w;  w += (size_t)NU * D * 4;
  float* agg_i = (float*)w;  w += (size_t)NI * D * 4;
  // zero region: counts_ui, counts_iu, zpart(4x1024) contiguous
  int* counts_ui = (int*)w;  w += (size_t)NI * 4;
  int* counts_iu = (int*)w;  w += (size_t)NU * 4;
  float* zpart = (float*)w;  w += 4096 * 4;
  float* zinv  = (float*)w;  w += 64;
  float* bq    = (float*)w;  w += 4 * D * 4;
  int* bsum_ui = (int*)w;    w += 1024 * 4;
  int* bsum_iu = (int*)w;    w += 1024 * 4;
  int* rp_ui = (int*)w;      w += (size_t)(NI + 4) * 4;
  int* rp_iu = (int*)w;      w += (size_t)(NU + 4) * 4;
  int* cs_ui = (int*)w;      w += (size_t)E * 4;
  int* cs_iu = (int*)w;      w += (size_t)E * 4;
  u16* Mt  = (u16*)w;        w += (size_t)4 * D * D * 2;
  u16* Wb  = (u16*)w;        w += (size_t)8 * D * D * 2;  // kwu,kwi,vwu,vwi x2 layers
  u16* xub = (u16*)w;        w += (size_t)NU * D * 2;
  u16* xib = (u16*)w;        w += (size_t)NI * D * 2;
  u16* Tk_u = (u16*)w;       w += (size_t)NU * D * 2;
  u16* Tk_i = (u16*)w;       w += (size_t)NI * D * 2;
  u8* Tq_u = (u8*)w;         w += (size_t)NU * D;
  u8* Tv_u = (u8*)w;         w += (size_t)NU * D;
  u8* Tq_i = (u8*)w;         w += (size_t)NI * D;
  u8* Tv_i = (u8*)w;

  float* out_u = (float*)d_out;
  float* out_i = out_u + (size_t)NU * D;

  prep_fused<<<dim3(128, 4), 128, 0, stream>>>(qwu, qbu, qwi, qbi, Wui, Wiu, Mt, bq);
  cast_w<<<dim3(128, 4), 256, 0, stream>>>(kwu, kwi, vwu, vwi, Wb);
  cast_x<<<(NU * D / 2 + 255) / 256, 256, 0, stream>>>(xu_in, xub, NU * D / 2);
  cast_x<<<(NI * D / 2 + 255) / 256, 256, 0, stream>>>(xi_in, xib, NI * D / 2);

  // ---- CSR build (edges constant across layers) ----
  int zn = NI + NU + 4096;
  zero_i<<<(zn + 255) / 256, 256, 0, stream>>>(counts_ui, zn);
  int geh = (E + 255) / 256;
  hist2<<<geh, 256, 0, stream>>>(ei_ui + E, ei_iu + E, counts_ui, counts_iu, E);
  int nbi = (NI + 1023) / 1024, nbu = (NU + 1023) / 1024;
  scan_phaseA<<<nbi, 256, 0, stream>>>(counts_ui, bsum_ui, NI);
  scan_phaseA<<<nbu, 256, 0, stream>>>(counts_iu, bsum_iu, NU);
  scan_phaseB<<<1, 1024, 0, stream>>>(bsum_ui, nbi);
  scan_phaseB<<<1, 1024, 0, stream>>>(bsum_iu, nbu);
  scan_phaseC<<<nbi, 256, 0, stream>>>(counts_ui, bsum_ui, rp_ui, counts_ui, NI, E);
  scan_phaseC<<<nbu, 256, 0, stream>>>(counts_iu, bsum_iu, rp_iu, counts_iu, NU, E);
  scatter2<<<geh, 256, 0, stream>>>(ei_ui, ei_ui + E, ei_iu, ei_iu + E,
                                    counts_ui, counts_iu, cs_ui, cs_iu, E);

  int gu = (NU + 63) / 64, gi = (NI + 63) / 64;
  int gau = (NU + 3) / 4, gai = (NI + 3) / 4;
  int gup = (NU * D + NI * D + 255) / 256;

  for (int l = 0; l < 2; ++l) {
    // users: q_ui (fused Mt), k_iu (kwu), v_ui (vwu)
    gemm3<<<dim3(gu, 3), 256, 0, stream>>>(
        xub,
        Mt + (size_t)l * D * D, bq + l * D,
        Wb + (size_t)(0 + l) * D * D, kbu + l * D,
        Wb + (size_t)(4 + l) * D * D, vbu + l * D,
        Tq_u, Tk_u, Tv_u, NU);
    // items: q_iu (fused Mt), k_ui (kwi), v_iu (vwi)
    gemm3<<<dim3(gi, 3), 256, 0, stream>>>(
        xib,
        Mt + (size_t)(2 + l) * D * D, bq + (2 + l) * D,
        Wb + (size_t)(2 + l) * D * D, kbi + l * D,
        Wb + (size_t)(6 + l) * D * D, vbi + l * D,
        Tq_i, Tk_i, Tv_i, NI);
    // ui edges: q/v from users, k from items, dst = items
    agg_pass<<<gai, 256, 0, stream>>>(Tq_u, Tk_i, Tv_u, rp_ui, cs_ui, agg_i,
                                      zpart + (size_t)(l * 2 + 0) * 1024, NI);
    // iu edges: q/v from items, k from users, dst = users
    agg_pass<<<gau, 256, 0, stream>>>(Tq_i, Tk_u, Tv_i, rp_iu, cs_iu, agg_u,
                                      zpart + (size_t)(l * 2 + 1) * 1024, NU);

    zreduce<<<2, 256, 0, stream>>>(zpart + (size_t)l * 2 * 1024, zinv + l * 2);
    if (l == 0)
      update_x<<<gup, 256, 0, stream>>>(xu_in, xi_in, agg_u, agg_i, zinv + l * 2,
                                        out_u, out_i, xub, xib, NU * D, NI * D, 1);
    else
      update_x<<<gup, 256, 0, stream>>>(out_u, out_i, agg_u, agg_i, zinv + l * 2,
                                        out_u, out_i, nullptr, nullptr, NU * D, NI * D, 0);
  }
}

// Round 6
// 526.253 us; speedup vs baseline: 4.7846x; 1.1785x over previous
//
#include <hip/hip_runtime.h>
#include <stdint.h>

#define D 128

typedef __attribute__((ext_vector_type(8))) short bf16x8;
typedef __attribute__((ext_vector_type(4))) float f32x4;
typedef __attribute__((ext_vector_type(2))) float f32x2;
typedef unsigned short u16;
typedef unsigned char u8;
typedef unsigned int u32;

static __device__ __forceinline__ float b2f(u16 u) {
  return __uint_as_float(((unsigned)u) << 16);
}
static __device__ __forceinline__ u16 f2b(float f) {
  unsigned u = __float_as_uint(f);
  return (u16)((u + 0x7fffu + ((u >> 16) & 1u)) >> 16);
}

// ------------------------------ fp8 e4m3 -----------------------------------
#if defined(__has_builtin)
#if __has_builtin(__builtin_amdgcn_cvt_pk_f32_fp8) && __has_builtin(__builtin_amdgcn_cvt_pk_fp8_f32)
#define HW_FP8 1
#endif
#endif

static __device__ __forceinline__ u8 enc_fp8(float f) {
#ifdef HW_FP8
  int p = __builtin_amdgcn_cvt_pk_fp8_f32(f, 0.f, 0, false);
  return (u8)(p & 0xff);
#else
  float a = fabsf(f);
  unsigned s = (__float_as_uint(f) >> 31) << 7;
  if (a < 7.8125e-3f) {
    int m = (int)(a * 512.f + 0.5f);
    if (m > 7) m = 7;
    return (u8)(s | m);
  }
  int e; float mant = frexpf(a, &e);
  int E = e + 6;
  int m = (int)((2.f * mant - 1.f) * 8.f + 0.5f);
  if (m == 8) { m = 0; E++; }
  if (E > 15 || (E == 15 && m > 6)) { E = 15; m = 6; }
  if (E < 1) return (u8)s;
  return (u8)(s | (E << 3) | m);
#endif
}

static __device__ __forceinline__ float dec1_fp8(u8 b) {
  int e = (b >> 3) & 15, m = b & 7;
  float mag = e ? ldexpf((float)(8 + m), e - 10) : ldexpf((float)m, -9);
  return (b & 128) ? -mag : mag;
}

static __device__ __forceinline__ void dec8_fp8(uint2 w, float* o) {
#ifdef HW_FP8
  f32x2 a = __builtin_amdgcn_cvt_pk_f32_fp8((int)w.x, false);
  f32x2 b = __builtin_amdgcn_cvt_pk_f32_fp8((int)w.x, true);
  f32x2 c = __builtin_amdgcn_cvt_pk_f32_fp8((int)w.y, false);
  f32x2 d = __builtin_amdgcn_cvt_pk_f32_fp8((int)w.y, true);
  o[0] = a.x; o[1] = a.y; o[2] = b.x; o[3] = b.y;
  o[4] = c.x; o[5] = c.y; o[6] = d.x; o[7] = d.y;
#else
  u8* p = (u8*)&w;
#pragma unroll
  for (int i = 0; i < 8; ++i) o[i] = dec1_fp8(p[i]);
#endif
}

// ---------------------------------------------------------------------------
// Fused q-projection weight: M[d][j] = sum_c qw[c][d]*W[c][j] (qW = x@M).
// Stored transposed Mt[c][j][d]; fused bias bq[c][j] = qb @ W.
// ---------------------------------------------------------------------------
__global__ void prep_fused(const float* __restrict__ qwu, const float* __restrict__ qbu,
                           const float* __restrict__ qwi, const float* __restrict__ qbi,
                           const float* __restrict__ Wui, const float* __restrict__ Wiu,
                           u16* __restrict__ Mt, float* __restrict__ bq) {
  int c = blockIdx.y, d = blockIdx.x, j = threadIdx.x;
  int l = c & 1, type = c >> 1;
  const float* qw = (type ? qwi : qwu) + l * D * D;
  const float* qb = (type ? qbi : qbu) + l * D;
  const float* W  = (type ? Wiu : Wui) + l * D * D;
  float acc = 0.f;
  for (int cc = 0; cc < D; ++cc) acc += qw[cc * D + d] * W[cc * D + j];
  Mt[((size_t)c * D + j) * D + d] = f2b(acc);
  if (d == 0) {
    float ba = 0.f;
    for (int cc = 0; cc < D; ++cc) ba += qb[cc] * W[cc * D + j];
    bq[c * D + j] = ba;
  }
}

__global__ void cast_w(const float* __restrict__ kwu, const float* __restrict__ kwi,
                       const float* __restrict__ vwu, const float* __restrict__ vwi,
                       u16* __restrict__ Wb) {
  int y = blockIdx.y;
  const float* s = (y == 0) ? kwu : (y == 1) ? kwi : (y == 2) ? vwu : vwi;
  int i = blockIdx.x * 256 + threadIdx.x;
  Wb[(size_t)y * 2 * D * D + i] = f2b(s[i]);
}

__global__ void cast_x(const float* __restrict__ x, u16* __restrict__ xb, int n2) {
  int i = blockIdx.x * 256 + threadIdx.x;
  if (i < n2) {
    float2 v = ((const float2*)x)[i];
    ((unsigned*)xb)[i] = (unsigned)f2b(v.x) | ((unsigned)f2b(v.y) << 16);
  }
}

__global__ void zero_i(int* __restrict__ p, int n) {
  int i = blockIdx.x * 256 + threadIdx.x;
  if (i < n) p[i] = 0;
}

// --------------------- CSR build via 2-level bucket sort --------------------
// Bucket = dst>>8 (256-dst window). Requires n <= 65536 (pack (dst<<16)|src).
// For NU=NI=50000: nb=196 buckets, ~3072 edges/bucket.

// Per-block LDS histogram of buckets, one global add per bucket per block.
__global__ __launch_bounds__(256) void bhist(const int* __restrict__ dui,
                                             const int* __restrict__ diu,
                                             int* __restrict__ cnt_ui,
                                             int* __restrict__ cnt_iu, int E) {
  __shared__ int h[256];
  int t = threadIdx.x;
  h[t] = 0;
  __syncthreads();
  const int* dp = blockIdx.y ? diu : dui;
  int e0 = blockIdx.x * 1024;
#pragma unroll
  for (int i = 0; i < 4; ++i) {
    int e = e0 + i * 256 + t;
    if (e < E) atomicAdd(&h[dp[e] >> 8], 1);
  }
  __syncthreads();
  int* out = blockIdx.y ? cnt_iu : cnt_ui;
  if (h[t]) atomicAdd(&out[t], h[t]);
}

// One block: exclusive scan of both types' bucket counts -> bases + cursors.
// Also writes row_ptr tails.
__global__ __launch_bounds__(256) void bscan(const int* __restrict__ cnt_ui,
                                             const int* __restrict__ cnt_iu,
                                             int* __restrict__ base_ui, int* __restrict__ base_iu,
                                             int* __restrict__ cur_ui, int* __restrict__ cur_iu,
                                             int* __restrict__ rp_ui, int* __restrict__ rp_iu,
                                             int nb_ui, int nb_iu, int n_ui, int n_iu, int E) {
  __shared__ int sh[256];
  int t = threadIdx.x;
  int v = (t < nb_ui) ? cnt_ui[t] : 0;
  sh[t] = v;
  __syncthreads();
  for (int off = 1; off < 256; off <<= 1) {
    int u = (t >= off) ? sh[t - off] : 0;
    __syncthreads();
    sh[t] += u;
    __syncthreads();
  }
  int ex = sh[t] - v;
  if (t < nb_ui) { base_ui[t] = ex; cur_ui[t] = ex; }
  if (t == 0) { base_ui[nb_ui] = E; rp_ui[n_ui] = E; }
  __syncthreads();
  v = (t < nb_iu) ? cnt_iu[t] : 0;
  sh[t] = v;
  __syncthreads();
  for (int off = 1; off < 256; off <<= 1) {
    int u = (t >= off) ? sh[t - off] : 0;
    __syncthreads();
    sh[t] += u;
    __syncthreads();
  }
  ex = sh[t] - v;
  if (t < nb_iu) { base_iu[t] = ex; cur_iu[t] = ex; }
  if (t == 0) { base_iu[nb_iu] = E; rp_iu[n_iu] = E; }
}

// Per-block bucket reservation + packed-pair scatter into bucket runs.
__global__ __launch_bounds__(256) void bscatter(
    const int* __restrict__ sui, const int* __restrict__ dui,
    const int* __restrict__ siu, const int* __restrict__ diu,
    int* __restrict__ cur_ui, int* __restrict__ cur_iu,
    u32* __restrict__ bb_ui, u32* __restrict__ bb_iu, int E) {
  __shared__ int h[256], rbase[256], c2[256];
  int t = threadIdx.x;
  const int* sp = blockIdx.y ? siu : sui;
  const int* dp = blockIdx.y ? diu : dui;
  int* gc = blockIdx.y ? cur_iu : cur_ui;
  u32* bb = blockIdx.y ? bb_iu : bb_ui;
  h[t] = 0;
  c2[t] = 0;
  __syncthreads();
  int e0 = blockIdx.x * 1024;
  u32 pr[4];
  int bk[4];
  bool act[4];
#pragma unroll
  for (int i = 0; i < 4; ++i) {
    int e = e0 + i * 256 + t;
    act[i] = e < E;
    if (act[i]) {
      int s = sp[e], d2 = dp[e];
      pr[i] = ((u32)d2 << 16) | (u32)s;
      bk[i] = d2 >> 8;
      atomicAdd(&h[bk[i]], 1);
    }
  }
  __syncthreads();
  if (h[t]) rbase[t] = atomicAdd(&gc[t], h[t]);
  __syncthreads();
#pragma unroll
  for (int i = 0; i < 4; ++i) {
    if (act[i]) {
      int r = atomicAdd(&c2[bk[i]], 1);
      bb[rbase[bk[i]] + r] = pr[i];
    }
  }
}

// One block per bucket: local counting sort -> cs (src list) + row_ptr.
__global__ __launch_bounds__(256) void bsort(
    const u32* __restrict__ bb_ui, const u32* __restrict__ bb_iu,
    const int* __restrict__ base_ui, const int* __restrict__ base_iu,
    int* __restrict__ rp_ui, int* __restrict__ rp_iu,
    int* __restrict__ cs_ui, int* __restrict__ cs_iu,
    int nb_ui, int n_ui, int n_iu) {
  int b = blockIdx.x;
  const u32* bb; const int* base; int* rp; int* cs; int n;
  if (b < nb_ui) { bb = bb_ui; base = base_ui; rp = rp_ui; cs = cs_ui; n = n_ui; }
  else { b -= nb_ui; bb = bb_iu; base = base_iu; rp = rp_iu; cs = cs_iu; n = n_iu; }
  int lo = base[b], hi = base[b + 1];
  __shared__ int h[256], sh[256], cur[256];
  int t = threadIdx.x;
  h[t] = 0;
  __syncthreads();
  for (int j = lo + t; j < hi; j += 256) atomicAdd(&h[(bb[j] >> 16) & 255], 1);
  __syncthreads();
  int v = h[t];
  sh[t] = v;
  __syncthreads();
  for (int off = 1; off < 256; off <<= 1) {
    int u = (t >= off) ? sh[t - off] : 0;
    __syncthreads();
    sh[t] += u;
    __syncthreads();
  }
  int ex = lo + sh[t] - v;
  int gd = (b << 8) + t;
  if (gd < n) rp[gd] = ex;
  cur[t] = ex;
  __syncthreads();
  for (int j = lo + t; j < hi; j += 256) {
    u32 pr = bb[j];
    int p = atomicAdd(&cur[(pr >> 16) & 255], 1);
    cs[p] = (int)(pr & 0xffffu);
  }
}

// ---------------------------------------------------------------------------
// Fused 3-way projection. y=0 -> q (fp8 out), y=1 -> k (bf16), y=2 -> v (fp8).
// MFMA layouts (m89/m91-verified): A[m=lane&15][k=quad*8+j];
// B[k=quad*8+j][n=lane&15]; C/D: col=lane&15, row=quad*4+reg.
// ---------------------------------------------------------------------------
__global__ __launch_bounds__(256) void gemm3(
    const u16* __restrict__ x,
    const u16* __restrict__ wq, const float* __restrict__ bq_,
    const u16* __restrict__ wk, const float* __restrict__ bk_,
    const u16* __restrict__ wv, const float* __restrict__ bv_,
    u8* __restrict__ Tq, u16* __restrict__ Tk, u8* __restrict__ Tv, int nrows) {
  __shared__ __align__(16) u16 wlds[128 * 136];
  int y = blockIdx.y;
  const u16* wt = (y == 0) ? wq : (y == 1) ? wk : wv;
  const float* bias = (y == 0) ? bq_ : (y == 1) ? bk_ : bv_;
  int t = threadIdx.x;
#pragma unroll
  for (int i = 0; i < 8; ++i) {
    int idx = t + 256 * i;
    int n = idx >> 4, kc = idx & 15;
    ((bf16x8*)wlds)[n * 17 + kc] = ((const bf16x8*)wt)[idx];
  }
  __syncthreads();
  int wave = t >> 6, lane = t & 63;
  int m = lane & 15, quad = lane >> 4;
  int row0 = blockIdx.x * 64 + wave * 16;
  int arow = row0 + m;
  const bf16x8* xv = (const bf16x8*)(x + (size_t)(arow < nrows ? arow : 0) * D);
  f32x4 acc[8];
#pragma unroll
  for (int n = 0; n < 8; ++n) acc[n] = (f32x4){0.f, 0.f, 0.f, 0.f};
#pragma unroll
  for (int kk = 0; kk < 4; ++kk) {
    bf16x8 a = xv[kk * 4 + quad];
#pragma unroll
    for (int n = 0; n < 8; ++n) {
      bf16x8 b = ((const bf16x8*)wlds)[(n * 16 + m) * 17 + kk * 4 + quad];
      acc[n] = __builtin_amdgcn_mfma_f32_16x16x32_bf16(a, b, acc[n], 0, 0, 0);
    }
  }
  if (y == 1) {
#pragma unroll
    for (int n = 0; n < 8; ++n) {
      float bb = bias[n * 16 + m];
#pragma unroll
      for (int r = 0; r < 4; ++r) {
        int orow = row0 + quad * 4 + r;
        if (orow < nrows) Tk[(size_t)orow * D + n * 16 + m] = f2b(acc[n][r] + bb);
      }
    }
  } else {
    u8* T8 = (y == 0) ? Tq : Tv;
#pragma unroll
    for (int n = 0; n < 8; ++n) {
      float bb = bias[n * 16 + m];
#pragma unroll
      for (int r = 0; r < 4; ++r) {
        int orow = row0 + quad * 4 + r;
        if (orow < nrows) T8[(size_t)orow * D + n * 16 + m] = enc_fp8(acc[n][r] + bb);
      }
    }
  }
}

// ---------------------------------------------------------------------------
// CSR aggregation: one wave per dst node, no atomics on agg. q/v fp8, k bf16.
// 16 lanes per edge (8 dims each), 4 edges in flight per wave.
// ---------------------------------------------------------------------------
__global__ __launch_bounds__(256) void agg_pass(
    const u8* __restrict__ Pq, const u16* __restrict__ Pk, const u8* __restrict__ Pv,
    const int* __restrict__ row_ptr, const int* __restrict__ csr_src,
    float* __restrict__ agg, float* __restrict__ zpart, int ndst) {
  int wave = threadIdx.x >> 6, lane = threadIdx.x & 63;
  int d = blockIdx.x * 4 + wave;
  int sub = lane & 15;
  int quad = lane >> 4;
  float z = 0.f;
  float acc[8] = {0.f, 0.f, 0.f, 0.f, 0.f, 0.f, 0.f, 0.f};
  if (d < ndst) {
    bf16x8 kf = *(const bf16x8*)(Pk + (size_t)d * D + sub * 8);
    float kx[8];
#pragma unroll
    for (int i = 0; i < 8; ++i) kx[i] = b2f((u16)((short*)&kf)[i]);
    int beg = row_ptr[d], end = row_ptr[d + 1];
    int iters = (end - beg + 3) >> 2;
    for (int it = 0; it < iters; ++it) {
      int j = beg + it * 4 + quad;
      bool act = j < end;
      int s = act ? csr_src[j] : 0;
      uint2 qw = *(const uint2*)(Pq + (size_t)s * D + sub * 8);
      uint2 vw = *(const uint2*)(Pv + (size_t)s * D + sub * 8);
      float qx[8], vx[8];
      dec8_fp8(qw, qx);
      dec8_fp8(vw, vx);
      float dot = 0.f;
#pragma unroll
      for (int i = 0; i < 8; ++i) dot = fmaf(qx[i], kx[i], dot);
#pragma unroll
      for (int off = 1; off <= 8; off <<= 1) dot += __shfl_xor(dot, off, 64);
      float sc = dot * 0.08838834764831845f;  // 1/sqrt(128)
      sc = (sc > 0.f) ? sc : 0.01f * sc;      // leaky_relu
      float p = act ? __expf(sc) : 0.f;
      if (sub == 0) z += p;
#pragma unroll
      for (int i = 0; i < 8; ++i) acc[i] = fmaf(p, vx[i], acc[i]);
    }
#pragma unroll
    for (int i = 0; i < 8; ++i) {
      acc[i] += __shfl_xor(acc[i], 16, 64);
      acc[i] += __shfl_xor(acc[i], 32, 64);
    }
    if (quad == 0) {
      float* ap = agg + (size_t)d * D + sub * 8;
      ((f32x4*)ap)[0] = (f32x4){acc[0], acc[1], acc[2], acc[3]};
      ((f32x4*)ap)[1] = (f32x4){acc[4], acc[5], acc[6], acc[7]};
    }
    z += __shfl_xor(z, 16, 64);
    z += __shfl_xor(z, 32, 64);
  }
  __shared__ float ps[4];
  if (lane == 0) ps[wave] = z;
  __syncthreads();
  if (threadIdx.x == 0)
    unsafeAtomicAdd(&zpart[blockIdx.x & 1023], ps[0] + ps[1] + ps[2] + ps[3]);
}

__global__ void zreduce(const float* __restrict__ zpart, float* __restrict__ zinv) {
  const float* zp = zpart + blockIdx.x * 1024;
  int t = threadIdx.x;
  float s = 0.f;
  for (int i = t; i < 1024; i += 256) s += zp[i];
  __shared__ float red[256];
  red[t] = s;
  __syncthreads();
  for (int k = 128; k > 0; k >>= 1) {
    if (t < k) red[t] += red[t + k];
    __syncthreads();
  }
  if (t == 0) zinv[blockIdx.x] = 1.0f / red[0];
}

__global__ void update_x(const float* __restrict__ xu, const float* __restrict__ xi,
                         const float* __restrict__ aggu, const float* __restrict__ aggi,
                         const float* __restrict__ zinv,
                         float* __restrict__ ou, float* __restrict__ oi,
                         u16* __restrict__ bu, u16* __restrict__ bi,
                         int nu, int ni, int wb) {
  int i = blockIdx.x * 256 + threadIdx.x;
  float zu = zinv[1];
  float zi = zinv[0];
  if (i < nu) {
    float v = xu[i] + aggu[i] * zu;
    ou[i] = v;
    if (wb) bu[i] = f2b(v);
  } else if (i < nu + ni) {
    int j = i - nu;
    float v = xi[j] + aggi[j] * zi;
    oi[j] = v;
    if (wb) bi[j] = f2b(v);
  }
}

extern "C" void kernel_launch(void* const* d_in, const int* in_sizes, int n_in,
                              void* d_out, int out_size, void* d_ws, size_t ws_size,
                              hipStream_t stream) {
  const float* xu_in = (const float*)d_in[0];
  const float* xi_in = (const float*)d_in[1];
  const int* ei_ui = (const int*)d_in[2];
  const int* ei_iu = (const int*)d_in[3];
  const float* qwu = (const float*)d_in[4];
  const float* qbu = (const float*)d_in[5];
  const float* kwu = (const float*)d_in[6];
  const float* kbu = (const float*)d_in[7];
  const float* vwu = (const float*)d_in[8];
  const float* vbu = (const float*)d_in[9];
  const float* qwi = (const float*)d_in[10];
  const float* qbi = (const float*)d_in[11];
  const float* kwi = (const float*)d_in[12];
  const float* kbi = (const float*)d_in[13];
  const float* vwi = (const float*)d_in[14];
  const float* vbi = (const float*)d_in[15];
  const float* Wui = (const float*)d_in[16];
  const float* Wiu = (const float*)d_in[17];

  int NU = in_sizes[0] / D;
  int NI = in_sizes[1] / D;
  int E  = in_sizes[2] / 2;

  // workspace layout (16B-aligned chunks)
  char* w = (char*)d_ws;
  float* agg_u = (float*)w;  w += (size_t)NU * D * 4;
  float* agg_i = (float*)w;  w += (size_t)NI * D * 4;
  // zero region: bcnt_ui[256], bcnt_iu[256], zpart[4096] contiguous
  int* bcnt_ui = (int*)w;    w += 256 * 4;
  int* bcnt_iu = (int*)w;    w += 256 * 4;
  float* zpart = (float*)w;  w += 4096 * 4;
  float* zinv  = (float*)w;  w += 64;
  float* bq    = (float*)w;  w += 4 * D * 4;
  int* base_ui = (int*)w;    w += 260 * 4;
  int* base_iu = (int*)w;    w += 260 * 4;
  int* cur_ui  = (int*)w;    w += 256 * 4;
  int* cur_iu  = (int*)w;    w += 256 * 4;
  int* rp_ui = (int*)w;      w += (size_t)(NI + 4) * 4;
  int* rp_iu = (int*)w;      w += (size_t)(NU + 4) * 4;
  int* cs_ui = (int*)w;      w += (size_t)E * 4;
  int* cs_iu = (int*)w;      w += (size_t)E * 4;
  u32* bb_ui = (u32*)w;      w += (size_t)E * 4;
  u32* bb_iu = (u32*)w;      w += (size_t)E * 4;
  u16* Mt  = (u16*)w;        w += (size_t)4 * D * D * 2;
  u16* Wb  = (u16*)w;        w += (size_t)8 * D * D * 2;
  u16* xub = (u16*)w;        w += (size_t)NU * D * 2;
  u16* xib = (u16*)w;        w += (size_t)NI * D * 2;
  u16* Tk_u = (u16*)w;       w += (size_t)NU * D * 2;
  u16* Tk_i = (u16*)w;       w += (size_t)NI * D * 2;
  u8* Tq_u = (u8*)w;         w += (size_t)NU * D;
  u8* Tv_u = (u8*)w;         w += (size_t)NU * D;
  u8* Tq_i = (u8*)w;         w += (size_t)NI * D;
  u8* Tv_i = (u8*)w;

  float* out_u = (float*)d_out;
  float* out_i = out_u + (size_t)NU * D;

  prep_fused<<<dim3(128, 4), 128, 0, stream>>>(qwu, qbu, qwi, qbi, Wui, Wiu, Mt, bq);
  cast_w<<<dim3(128, 4), 256, 0, stream>>>(kwu, kwi, vwu, vwi, Wb);
  cast_x<<<(NU * D / 2 + 255) / 256, 256, 0, stream>>>(xu_in, xub, NU * D / 2);
  cast_x<<<(NI * D / 2 + 255) / 256, 256, 0, stream>>>(xi_in, xib, NI * D / 2);

  // ---- CSR build via 2-level bucket sort (edges constant across layers) ----
  int nb_ui = (NI + 255) >> 8;  // ui edges: dst = items
  int nb_iu = (NU + 255) >> 8;  // iu edges: dst = users
  zero_i<<<18, 256, 0, stream>>>(bcnt_ui, 512 + 4096);
  int geb = (E + 1023) / 1024;
  bhist<<<dim3(geb, 2), 256, 0, stream>>>(ei_ui + E, ei_iu + E, bcnt_ui, bcnt_iu, E);
  bscan<<<1, 256, 0, stream>>>(bcnt_ui, bcnt_iu, base_ui, base_iu, cur_ui, cur_iu,
                               rp_ui, rp_iu, nb_ui, nb_iu, NI, NU, E);
  bscatter<<<dim3(geb, 2), 256, 0, stream>>>(ei_ui, ei_ui + E, ei_iu, ei_iu + E,
                                             cur_ui, cur_iu, bb_ui, bb_iu, E);
  bsort<<<nb_ui + nb_iu, 256, 0, stream>>>(bb_ui, bb_iu, base_ui, base_iu,
                                           rp_ui, rp_iu, cs_ui, cs_iu, nb_ui, NI, NU);

  int gu = (NU + 63) / 64, gi = (NI + 63) / 64;
  int gau = (NU + 3) / 4, gai = (NI + 3) / 4;
  int gup = (NU * D + NI * D + 255) / 256;

  for (int l = 0; l < 2; ++l) {
    // users: q_ui (fused Mt), k_iu (kwu), v_ui (vwu)
    gemm3<<<dim3(gu, 3), 256, 0, stream>>>(
        xub,
        Mt + (size_t)l * D * D, bq + l * D,
        Wb + (size_t)(0 + l) * D * D, kbu + l * D,
        Wb + (size_t)(4 + l) * D * D, vbu + l * D,
        Tq_u, Tk_u, Tv_u, NU);
    // items: q_iu (fused Mt), k_ui (kwi), v_iu (vwi)
    gemm3<<<dim3(gi, 3), 256, 0, stream>>>(
        xib,
        Mt + (size_t)(2 + l) * D * D, bq + (2 + l) * D,
        Wb + (size_t)(2 + l) * D * D, kbi + l * D,
        Wb + (size_t)(6 + l) * D * D, vbi + l * D,
        Tq_i, Tk_i, Tv_i, NI);
    // ui edges: q/v from users, k from items, dst = items
    agg_pass<<<gai, 256, 0, stream>>>(Tq_u, Tk_i, Tv_u, rp_ui, cs_ui, agg_i,
                                      zpart + (size_t)(l * 2 + 0) * 1024, NI);
    // iu edges: q/v from items, k from users, dst = users
    agg_pass<<<gau, 256, 0, stream>>>(Tq_i, Tk_u, Tv_i, rp_iu, cs_iu, agg_u,
                                      zpart + (size_t)(l * 2 + 1) * 1024, NU);

    zreduce<<<2, 256, 0, stream>>>(zpart + (size_t)l * 2 * 1024, zinv + l * 2);
    if (l == 0)
      update_x<<<gup, 256, 0, stream>>>(xu_in, xi_in, agg_u, agg_i, zinv + l * 2,
                                        out_u, out_i, xub, xib, NU * D, NI * D, 1);
    else
      update_x<<<gup, 256, 0, stream>>>(out_u, out_i, agg_u, agg_i, zinv + l * 2,
                                        out_u, out_i, nullptr, nullptr, NU * D, NI * D, 0);
  }
}

// Round 7
// 498.109 us; speedup vs baseline: 5.0550x; 1.0565x over previous
//
#include <hip/hip_runtime.h>
#include <stdint.h>

#define D 128

typedef __attribute__((ext_vector_type(8))) short bf16x8;
typedef __attribute__((ext_vector_type(4))) float f32x4;
typedef __attribute__((ext_vector_type(2))) float f32x2;
typedef unsigned short u16;
typedef unsigned char u8;
typedef unsigned int u32;

static __device__ __forceinline__ float b2f(u16 u) {
  return __uint_as_float(((unsigned)u) << 16);
}
static __device__ __forceinline__ u16 f2b(float f) {
  unsigned u = __float_as_uint(f);
  return (u16)((u + 0x7fffu + ((u >> 16) & 1u)) >> 16);
}

// ------------------------------ fp8 e4m3 -----------------------------------
#if defined(__has_builtin)
#if __has_builtin(__builtin_amdgcn_cvt_pk_f32_fp8) && __has_builtin(__builtin_amdgcn_cvt_pk_fp8_f32)
#define HW_FP8 1
#endif
#endif

static __device__ __forceinline__ u8 enc_fp8(float f) {
#ifdef HW_FP8
  int p = __builtin_amdgcn_cvt_pk_fp8_f32(f, 0.f, 0, false);
  return (u8)(p & 0xff);
#else
  float a = fabsf(f);
  unsigned s = (__float_as_uint(f) >> 31) << 7;
  if (a < 7.8125e-3f) {
    int m = (int)(a * 512.f + 0.5f);
    if (m > 7) m = 7;
    return (u8)(s | m);
  }
  int e; float mant = frexpf(a, &e);
  int E = e + 6;
  int m = (int)((2.f * mant - 1.f) * 8.f + 0.5f);
  if (m == 8) { m = 0; E++; }
  if (E > 15 || (E == 15 && m > 6)) { E = 15; m = 6; }
  if (E < 1) return (u8)s;
  return (u8)(s | (E << 3) | m);
#endif
}

static __device__ __forceinline__ float dec1_fp8(u8 b) {
  int e = (b >> 3) & 15, m = b & 7;
  float mag = e ? ldexpf((float)(8 + m), e - 10) : ldexpf((float)m, -9);
  return (b & 128) ? -mag : mag;
}

static __device__ __forceinline__ void dec8_fp8(u32 lo, u32 hi, float* o) {
#ifdef HW_FP8
  f32x2 a = __builtin_amdgcn_cvt_pk_f32_fp8((int)lo, false);
  f32x2 b = __builtin_amdgcn_cvt_pk_f32_fp8((int)lo, true);
  f32x2 c = __builtin_amdgcn_cvt_pk_f32_fp8((int)hi, false);
  f32x2 d = __builtin_amdgcn_cvt_pk_f32_fp8((int)hi, true);
  o[0] = a.x; o[1] = a.y; o[2] = b.x; o[3] = b.y;
  o[4] = c.x; o[5] = c.y; o[6] = d.x; o[7] = d.y;
#else
  u32 w[2] = {lo, hi};
  u8* p = (u8*)w;
#pragma unroll
  for (int i = 0; i < 8; ++i) o[i] = dec1_fp8(p[i]);
#endif
}

// ---------------------------------------------------------------------------
// Fused q-projection weight: M[d][j] = sum_c qw[c][d]*W[c][j] (qW = x@M).
// Stored transposed Mt[c][j][d]; fused bias bq[c][j] = qb @ W.
// ---------------------------------------------------------------------------
__global__ void prep_fused(const float* __restrict__ qwu, const float* __restrict__ qbu,
                           const float* __restrict__ qwi, const float* __restrict__ qbi,
                           const float* __restrict__ Wui, const float* __restrict__ Wiu,
                           u16* __restrict__ Mt, float* __restrict__ bq) {
  int c = blockIdx.y, d = blockIdx.x, j = threadIdx.x;
  int l = c & 1, type = c >> 1;
  const float* qw = (type ? qwi : qwu) + l * D * D;
  const float* qb = (type ? qbi : qbu) + l * D;
  const float* W  = (type ? Wiu : Wui) + l * D * D;
  float acc = 0.f;
  for (int cc = 0; cc < D; ++cc) acc += qw[cc * D + d] * W[cc * D + j];
  Mt[((size_t)c * D + j) * D + d] = f2b(acc);
  if (d == 0) {
    float ba = 0.f;
    for (int cc = 0; cc < D; ++cc) ba += qb[cc] * W[cc * D + j];
    bq[c * D + j] = ba;
  }
}

__global__ void cast_w(const float* __restrict__ kwu, const float* __restrict__ kwi,
                       const float* __restrict__ vwu, const float* __restrict__ vwi,
                       u16* __restrict__ Wb) {
  int y = blockIdx.y;
  const float* s = (y == 0) ? kwu : (y == 1) ? kwi : (y == 2) ? vwu : vwi;
  int i = blockIdx.x * 256 + threadIdx.x;
  Wb[(size_t)y * 2 * D * D + i] = f2b(s[i]);
}

__global__ void cast_x(const float* __restrict__ x, u16* __restrict__ xb, int n2) {
  int i = blockIdx.x * 256 + threadIdx.x;
  if (i < n2) {
    float2 v = ((const float2*)x)[i];
    ((unsigned*)xb)[i] = (unsigned)f2b(v.x) | ((unsigned)f2b(v.y) << 16);
  }
}

__global__ void zero_i(int* __restrict__ p, int n) {
  int i = blockIdx.x * 256 + threadIdx.x;
  if (i < n) p[i] = 0;
}

// --------------------- CSR build via 2-level bucket sort --------------------
__global__ __launch_bounds__(256) void bhist(const int* __restrict__ dui,
                                             const int* __restrict__ diu,
                                             int* __restrict__ cnt_ui,
                                             int* __restrict__ cnt_iu, int E) {
  __shared__ int h[256];
  int t = threadIdx.x;
  h[t] = 0;
  __syncthreads();
  const int* dp = blockIdx.y ? diu : dui;
  int e0 = blockIdx.x * 1024;
#pragma unroll
  for (int i = 0; i < 4; ++i) {
    int e = e0 + i * 256 + t;
    if (e < E) atomicAdd(&h[dp[e] >> 8], 1);
  }
  __syncthreads();
  int* out = blockIdx.y ? cnt_iu : cnt_ui;
  if (h[t]) atomicAdd(&out[t], h[t]);
}

__global__ __launch_bounds__(256) void bscan(const int* __restrict__ cnt_ui,
                                             const int* __restrict__ cnt_iu,
                                             int* __restrict__ base_ui, int* __restrict__ base_iu,
                                             int* __restrict__ cur_ui, int* __restrict__ cur_iu,
                                             int* __restrict__ rp_ui, int* __restrict__ rp_iu,
                                             int nb_ui, int nb_iu, int n_ui, int n_iu, int E) {
  __shared__ int sh[256];
  int t = threadIdx.x;
  int v = (t < nb_ui) ? cnt_ui[t] : 0;
  sh[t] = v;
  __syncthreads();
  for (int off = 1; off < 256; off <<= 1) {
    int u = (t >= off) ? sh[t - off] : 0;
    __syncthreads();
    sh[t] += u;
    __syncthreads();
  }
  int ex = sh[t] - v;
  if (t < nb_ui) { base_ui[t] = ex; cur_ui[t] = ex; }
  if (t == 0) { base_ui[nb_ui] = E; rp_ui[n_ui] = E; }
  __syncthreads();
  v = (t < nb_iu) ? cnt_iu[t] : 0;
  sh[t] = v;
  __syncthreads();
  for (int off = 1; off < 256; off <<= 1) {
    int u = (t >= off) ? sh[t - off] : 0;
    __syncthreads();
    sh[t] += u;
    __syncthreads();
  }
  ex = sh[t] - v;
  if (t < nb_iu) { base_iu[t] = ex; cur_iu[t] = ex; }
  if (t == 0) { base_iu[nb_iu] = E; rp_iu[n_iu] = E; }
}

__global__ __launch_bounds__(256) void bscatter(
    const int* __restrict__ sui, const int* __restrict__ dui,
    const int* __restrict__ siu, const int* __restrict__ diu,
    int* __restrict__ cur_ui, int* __restrict__ cur_iu,
    u32* __restrict__ bb_ui, u32* __restrict__ bb_iu, int E) {
  __shared__ int h[256], rbase[256], c2[256];
  int t = threadIdx.x;
  const int* sp = blockIdx.y ? siu : sui;
  const int* dp = blockIdx.y ? diu : dui;
  int* gc = blockIdx.y ? cur_iu : cur_ui;
  u32* bb = blockIdx.y ? bb_iu : bb_ui;
  h[t] = 0;
  c2[t] = 0;
  __syncthreads();
  int e0 = blockIdx.x * 1024;
  u32 pr[4];
  int bk[4];
  bool act[4];
#pragma unroll
  for (int i = 0; i < 4; ++i) {
    int e = e0 + i * 256 + t;
    act[i] = e < E;
    if (act[i]) {
      int s = sp[e], d2 = dp[e];
      pr[i] = ((u32)d2 << 16) | (u32)s;
      bk[i] = d2 >> 8;
      atomicAdd(&h[bk[i]], 1);
    }
  }
  __syncthreads();
  if (h[t]) rbase[t] = atomicAdd(&gc[t], h[t]);
  __syncthreads();
#pragma unroll
  for (int i = 0; i < 4; ++i) {
    if (act[i]) {
      int r = atomicAdd(&c2[bk[i]], 1);
      bb[rbase[bk[i]] + r] = pr[i];
    }
  }
}

__global__ __launch_bounds__(256) void bsort(
    const u32* __restrict__ bb_ui, const u32* __restrict__ bb_iu,
    const int* __restrict__ base_ui, const int* __restrict__ base_iu,
    int* __restrict__ rp_ui, int* __restrict__ rp_iu,
    int* __restrict__ cs_ui, int* __restrict__ cs_iu,
    int nb_ui, int n_ui, int n_iu) {
  int b = blockIdx.x;
  const u32* bb; const int* base; int* rp; int* cs; int n;
  if (b < nb_ui) { bb = bb_ui; base = base_ui; rp = rp_ui; cs = cs_ui; n = n_ui; }
  else { b -= nb_ui; bb = bb_iu; base = base_iu; rp = rp_iu; cs = cs_iu; n = n_iu; }
  int lo = base[b], hi = base[b + 1];
  __shared__ int h[256], sh[256], cur[256];
  int t = threadIdx.x;
  h[t] = 0;
  __syncthreads();
  for (int j = lo + t; j < hi; j += 256) atomicAdd(&h[(bb[j] >> 16) & 255], 1);
  __syncthreads();
  int v = h[t];
  sh[t] = v;
  __syncthreads();
  for (int off = 1; off < 256; off <<= 1) {
    int u = (t >= off) ? sh[t - off] : 0;
    __syncthreads();
    sh[t] += u;
    __syncthreads();
  }
  int ex = lo + sh[t] - v;
  int gd = (b << 8) + t;
  if (gd < n) rp[gd] = ex;
  cur[t] = ex;
  __syncthreads();
  for (int j = lo + t; j < hi; j += 256) {
    u32 pr = bb[j];
    int p = atomicAdd(&cur[(pr >> 16) & 255], 1);
    cs[p] = (int)(pr & 0xffffu);
  }
}

// ---------------------------------------------------------------------------
// Merged 3-way projection for BOTH node sets. blockIdx.x < gu -> users,
// else items. blockIdx.y: 0 -> q (fp8 into Tqv lo-bytes), 1 -> k (bf16),
// 2 -> v (fp8 into Tqv hi-bytes). Tqv row (256 B):
// [q0..7 | v0..7 | q8..15 | v8..15 | ...] so dim d's q byte sits at
// (d>>3)*16 + (d&7), v at +8.
// MFMA layouts (m89/m91-verified): A[m=lane&15][k=quad*8+j];
// B[k=quad*8+j][n=lane&15]; C/D: col=lane&15, row=quad*4+reg.
// ---------------------------------------------------------------------------
__global__ __launch_bounds__(256) void gemm3(
    const u16* __restrict__ xu, const u16* __restrict__ xi,
    const u16* __restrict__ wqu, const u16* __restrict__ wku, const u16* __restrict__ wvu,
    const float* __restrict__ bqu, const float* __restrict__ bku, const float* __restrict__ bvu,
    const u16* __restrict__ wqi, const u16* __restrict__ wki, const u16* __restrict__ wvi,
    const float* __restrict__ bqi, const float* __restrict__ bki, const float* __restrict__ bvi,
    u8* __restrict__ Tqv_u, u16* __restrict__ Tk_u,
    u8* __restrict__ Tqv_i, u16* __restrict__ Tk_i,
    int gu, int nu, int ni) {
  __shared__ __align__(16) u16 wlds[128 * 136];
  int bx = blockIdx.x, y = blockIdx.y;
  bool item = bx >= gu;
  if (item) bx -= gu;
  const u16* x = item ? xi : xu;
  int nrows = item ? ni : nu;
  const u16* wt; const float* bias;
  if (y == 0)      { wt = item ? wqi : wqu; bias = item ? bqi : bqu; }
  else if (y == 1) { wt = item ? wki : wku; bias = item ? bki : bku; }
  else             { wt = item ? wvi : wvu; bias = item ? bvi : bvu; }
  u8* Tqv = item ? Tqv_i : Tqv_u;
  u16* Tk = item ? Tk_i : Tk_u;

  int t = threadIdx.x;
#pragma unroll
  for (int i = 0; i < 8; ++i) {
    int idx = t + 256 * i;
    int n = idx >> 4, kc = idx & 15;
    ((bf16x8*)wlds)[n * 17 + kc] = ((const bf16x8*)wt)[idx];
  }
  __syncthreads();
  int wave = t >> 6, lane = t & 63;
  int m = lane & 15, quad = lane >> 4;
  int row0 = bx * 64 + wave * 16;
  int arow = row0 + m;
  const bf16x8* xv = (const bf16x8*)(x + (size_t)(arow < nrows ? arow : 0) * D);
  f32x4 acc[8];
#pragma unroll
  for (int n = 0; n < 8; ++n) acc[n] = (f32x4){0.f, 0.f, 0.f, 0.f};
#pragma unroll
  for (int kk = 0; kk < 4; ++kk) {
    bf16x8 a = xv[kk * 4 + quad];
#pragma unroll
    for (int n = 0; n < 8; ++n) {
      bf16x8 b = ((const bf16x8*)wlds)[(n * 16 + m) * 17 + kk * 4 + quad];
      acc[n] = __builtin_amdgcn_mfma_f32_16x16x32_bf16(a, b, acc[n], 0, 0, 0);
    }
  }
  if (y == 1) {
#pragma unroll
    for (int n = 0; n < 8; ++n) {
      float bb = bias[n * 16 + m];
#pragma unroll
      for (int r = 0; r < 4; ++r) {
        int orow = row0 + quad * 4 + r;
        if (orow < nrows) Tk[(size_t)orow * D + n * 16 + m] = f2b(acc[n][r] + bb);
      }
    }
  } else {
    int vo = (y == 0) ? 0 : 8;
#pragma unroll
    for (int n = 0; n < 8; ++n) {
      float bb = bias[n * 16 + m];
      int dim = n * 16 + m;
      int boff = ((dim >> 3) << 4) + (dim & 7) + vo;
#pragma unroll
      for (int r = 0; r < 4; ++r) {
        int orow = row0 + quad * 4 + r;
        if (orow < nrows) Tqv[(size_t)orow * 256 + boff] = enc_fp8(acc[n][r] + bb);
      }
    }
  }
}

// ---------------------------------------------------------------------------
// Merged CSR aggregation for both edge types: blockIdx.x < gai -> ui
// (q/v users, k items, dst items), else iu. One wave per dst node, no agg
// atomics. q+v interleaved fp8 row (one uint4 per lane per edge), k bf16.
// ---------------------------------------------------------------------------
__global__ __launch_bounds__(256) void agg_pass(
    const u8* __restrict__ Tqv_u, const u16* __restrict__ Tk_u,
    const u8* __restrict__ Tqv_i, const u16* __restrict__ Tk_i,
    const int* __restrict__ rp_ui, const int* __restrict__ cs_ui,
    const int* __restrict__ rp_iu, const int* __restrict__ cs_iu,
    float* __restrict__ agg_u, float* __restrict__ agg_i,
    float* __restrict__ zpart, int gai, int ni, int nu) {
  int bx = blockIdx.x;
  const u8* Pqv; const u16* Pk; const int* rp; const int* cs;
  float* agg; float* zp; int ndst;
  if (bx < gai) { Pqv = Tqv_u; Pk = Tk_i; rp = rp_ui; cs = cs_ui; agg = agg_i; zp = zpart; ndst = ni; }
  else { bx -= gai; Pqv = Tqv_i; Pk = Tk_u; rp = rp_iu; cs = cs_iu; agg = agg_u; zp = zpart + 1024; ndst = nu; }
  int wave = threadIdx.x >> 6, lane = threadIdx.x & 63;
  int d = bx * 4 + wave;
  int sub = lane & 15;
  int quad = lane >> 4;
  float z = 0.f;
  float acc[8] = {0.f, 0.f, 0.f, 0.f, 0.f, 0.f, 0.f, 0.f};
  if (d < ndst) {
    bf16x8 kf = *(const bf16x8*)(Pk + (size_t)d * D + sub * 8);
    float kx[8];
#pragma unroll
    for (int i = 0; i < 8; ++i) kx[i] = b2f((u16)((short*)&kf)[i]);
    int beg = rp[d], end = rp[d + 1];
    int iters = (end - beg + 3) >> 2;
    for (int it = 0; it < iters; ++it) {
      int j = beg + it * 4 + quad;
      bool act = j < end;
      int s = act ? cs[j] : 0;
      uint4 w = *(const uint4*)(Pqv + (size_t)s * 256 + sub * 16);
      float qx[8], vx[8];
      dec8_fp8(w.x, w.y, qx);
      dec8_fp8(w.z, w.w, vx);
      float dot = 0.f;
#pragma unroll
      for (int i = 0; i < 8; ++i) dot = fmaf(qx[i], kx[i], dot);
#pragma unroll
      for (int off = 1; off <= 8; off <<= 1) dot += __shfl_xor(dot, off, 64);
      float sc = dot * 0.08838834764831845f;  // 1/sqrt(128)
      sc = (sc > 0.f) ? sc : 0.01f * sc;      // leaky_relu
      float p = act ? __expf(sc) : 0.f;
      if (sub == 0) z += p;
#pragma unroll
      for (int i = 0; i < 8; ++i) acc[i] = fmaf(p, vx[i], acc[i]);
    }
#pragma unroll
    for (int i = 0; i < 8; ++i) {
      acc[i] += __shfl_xor(acc[i], 16, 64);
      acc[i] += __shfl_xor(acc[i], 32, 64);
    }
    if (quad == 0) {
      float* ap = agg + (size_t)d * D + sub * 8;
      ((f32x4*)ap)[0] = (f32x4){acc[0], acc[1], acc[2], acc[3]};
      ((f32x4*)ap)[1] = (f32x4){acc[4], acc[5], acc[6], acc[7]};
    }
    z += __shfl_xor(z, 16, 64);
    z += __shfl_xor(z, 32, 64);
  }
  __shared__ float ps[4];
  if (lane == 0) ps[wave] = z;
  __syncthreads();
  if (threadIdx.x == 0)
    unsafeAtomicAdd(&zp[blockIdx.x & 1023], ps[0] + ps[1] + ps[2] + ps[3]);
}

__global__ void zreduce(const float* __restrict__ zpart, float* __restrict__ zinv) {
  const float* zp = zpart + blockIdx.x * 1024;
  int t = threadIdx.x;
  float s = 0.f;
  for (int i = t; i < 1024; i += 256) s += zp[i];
  __shared__ float red[256];
  red[t] = s;
  __syncthreads();
  for (int k = 128; k > 0; k >>= 1) {
    if (t < k) red[t] += red[t + k];
    __syncthreads();
  }
  if (t == 0) zinv[blockIdx.x] = 1.0f / red[0];
}

__global__ void update_x(const float* __restrict__ xu, const float* __restrict__ xi,
                         const float* __restrict__ aggu, const float* __restrict__ aggi,
                         const float* __restrict__ zinv,
                         float* __restrict__ ou, float* __restrict__ oi,
                         u16* __restrict__ bu, u16* __restrict__ bi,
                         int nu, int ni, int wb) {
  int i = blockIdx.x * 256 + threadIdx.x;
  float zu = zinv[1];
  float zi = zinv[0];
  if (i < nu) {
    float v = xu[i] + aggu[i] * zu;
    ou[i] = v;
    if (wb) bu[i] = f2b(v);
  } else if (i < nu + ni) {
    int j = i - nu;
    float v = xi[j] + aggi[j] * zi;
    oi[j] = v;
    if (wb) bi[j] = f2b(v);
  }
}

extern "C" void kernel_launch(void* const* d_in, const int* in_sizes, int n_in,
                              void* d_out, int out_size, void* d_ws, size_t ws_size,
                              hipStream_t stream) {
  const float* xu_in = (const float*)d_in[0];
  const float* xi_in = (const float*)d_in[1];
  const int* ei_ui = (const int*)d_in[2];
  const int* ei_iu = (const int*)d_in[3];
  const float* qwu = (const float*)d_in[4];
  const float* qbu = (const float*)d_in[5];
  const float* kwu = (const float*)d_in[6];
  const float* kbu = (const float*)d_in[7];
  const float* vwu = (const float*)d_in[8];
  const float* vbu = (const float*)d_in[9];
  const float* qwi = (const float*)d_in[10];
  const float* qbi = (const float*)d_in[11];
  const float* kwi = (const float*)d_in[12];
  const float* kbi = (const float*)d_in[13];
  const float* vwi = (const float*)d_in[14];
  const float* vbi = (const float*)d_in[15];
  const float* Wui = (const float*)d_in[16];
  const float* Wiu = (const float*)d_in[17];

  int NU = in_sizes[0] / D;
  int NI = in_sizes[1] / D;
  int E  = in_sizes[2] / 2;

  // workspace layout (16B-aligned chunks)
  char* w = (char*)d_ws;
  float* agg_u = (float*)w;  w += (size_t)NU * D * 4;
  float* agg_i = (float*)w;  w += (size_t)NI * D * 4;
  // zero region: bcnt_ui[256], bcnt_iu[256], zpart[4096] contiguous
  int* bcnt_ui = (int*)w;    w += 256 * 4;
  int* bcnt_iu = (int*)w;    w += 256 * 4;
  float* zpart = (float*)w;  w += 4096 * 4;
  float* zinv  = (float*)w;  w += 64;
  float* bq    = (float*)w;  w += 4 * D * 4;
  int* base_ui = (int*)w;    w += 260 * 4;
  int* base_iu = (int*)w;    w += 260 * 4;
  int* cur_ui  = (int*)w;    w += 256 * 4;
  int* cur_iu  = (int*)w;    w += 256 * 4;
  int* rp_ui = (int*)w;      w += (size_t)(NI + 4) * 4;
  int* rp_iu = (int*)w;      w += (size_t)(NU + 4) * 4;
  int* cs_ui = (int*)w;      w += (size_t)E * 4;
  int* cs_iu = (int*)w;      w += (size_t)E * 4;
  u32* bb_ui = (u32*)w;      w += (size_t)E * 4;
  u32* bb_iu = (u32*)w;      w += (size_t)E * 4;
  u16* Mt  = (u16*)w;        w += (size_t)4 * D * D * 2;
  u16* Wb  = (u16*)w;        w += (size_t)8 * D * D * 2;
  u16* xub = (u16*)w;        w += (size_t)NU * D * 2;
  u16* xib = (u16*)w;        w += (size_t)NI * D * 2;
  u16* Tk_u = (u16*)w;       w += (size_t)NU * D * 2;
  u16* Tk_i = (u16*)w;       w += (size_t)NI * D * 2;
  u8* Tqv_u = (u8*)w;        w += (size_t)NU * 256;
  u8* Tqv_i = (u8*)w;

  float* out_u = (float*)d_out;
  float* out_i = out_u + (size_t)NU * D;

  prep_fused<<<dim3(128, 4), 128, 0, stream>>>(qwu, qbu, qwi, qbi, Wui, Wiu, Mt, bq);
  cast_w<<<dim3(128, 4), 256, 0, stream>>>(kwu, kwi, vwu, vwi, Wb);
  cast_x<<<(NU * D / 2 + 255) / 256, 256, 0, stream>>>(xu_in, xub, NU * D / 2);
  cast_x<<<(NI * D / 2 + 255) / 256, 256, 0, stream>>>(xi_in, xib, NI * D / 2);

  // ---- CSR build via 2-level bucket sort (edges constant across layers) ----
  int nb_ui = (NI + 255) >> 8;
  int nb_iu = (NU + 255) >> 8;
  zero_i<<<18, 256, 0, stream>>>(bcnt_ui, 512 + 4096);
  int geb = (E + 1023) / 1024;
  bhist<<<dim3(geb, 2), 256, 0, stream>>>(ei_ui + E, ei_iu + E, bcnt_ui, bcnt_iu, E);
  bscan<<<1, 256, 0, stream>>>(bcnt_ui, bcnt_iu, base_ui, base_iu, cur_ui, cur_iu,
                               rp_ui, rp_iu, nb_ui, nb_iu, NI, NU, E);
  bscatter<<<dim3(geb, 2), 256, 0, stream>>>(ei_ui, ei_ui + E, ei_iu, ei_iu + E,
                                             cur_ui, cur_iu, bb_ui, bb_iu, E);
  bsort<<<nb_ui + nb_iu, 256, 0, stream>>>(bb_ui, bb_iu, base_ui, base_iu,
                                           rp_ui, rp_iu, cs_ui, cs_iu, nb_ui, NI, NU);

  int gu = (NU + 63) / 64, gi = (NI + 63) / 64;
  int gau = (NU + 3) / 4, gai = (NI + 3) / 4;
  int gup = (NU * D + NI * D + 255) / 256;

  for (int l = 0; l < 2; ++l) {
    gemm3<<<dim3(gu + gi, 3), 256, 0, stream>>>(
        xub, xib,
        Mt + (size_t)l * D * D, Wb + (size_t)(0 + l) * D * D, Wb + (size_t)(4 + l) * D * D,
        bq + l * D, kbu + l * D, vbu + l * D,
        Mt + (size_t)(2 + l) * D * D, Wb + (size_t)(2 + l) * D * D, Wb + (size_t)(6 + l) * D * D,
        bq + (2 + l) * D, kbi + l * D, vbi + l * D,
        Tqv_u, Tk_u, Tqv_i, Tk_i, gu, NU, NI);
    agg_pass<<<gai + gau, 256, 0, stream>>>(
        Tqv_u, Tk_u, Tqv_i, Tk_i, rp_ui, cs_ui, rp_iu, cs_iu,
        agg_u, agg_i, zpart + (size_t)l * 2 * 1024, gai, NI, NU);
    zreduce<<<2, 256, 0, stream>>>(zpart + (size_t)l * 2 * 1024, zinv + l * 2);
    if (l == 0)
      update_x<<<gup, 256, 0, stream>>>(xu_in, xi_in, agg_u, agg_i, zinv + l * 2,
                                        out_u, out_i, xub, xib, NU * D, NI * D, 1);
    else
      update_x<<<gup, 256, 0, stream>>>(out_u, out_i, agg_u, agg_i, zinv + l * 2,
                                        out_u, out_i, nullptr, nullptr, NU * D, NI * D, 0);
  }
}